// Round 5
// baseline (404.096 us; speedup 1.0000x reference)
//
#include <hip/hip_runtime.h>

#define EPSB 1e-5f
#define B_ 4
#define N_ 256
#define H_ 16
#define D_ 5
#define E_ 4096
#define M_PAIR (B_*N_*N_)   // 262144

typedef __attribute__((ext_vector_type(8))) short short8;
typedef __attribute__((ext_vector_type(4))) float f32x4;

// ---- stats slot offsets (floats) in ws ----
enum {
  SO_ANGX = 0,
  SO_CENX = 2,
  SO_ANG2 = 16,  SO_ANG2Q = 32,
  SO_CEN2 = 48,  SO_CEN2Q = 64,
  SO_C1   = 96,  SO_C1Q   = 160,
  SO_C2   = 224, SO_C2Q   = 352,
  SO_C3   = 480, SO_C3Q   = 736,
  SO_FC   = 992, SO_FCQ   = 1008,
  SO_ET2  = 1056, SO_ET2Q = 1072,
  SO_EL2  = 1120, SO_EL2Q = 1136,
  SO_EV2  = 1184, SO_EV2Q = 1200,
  SO_G1   = 1216, SO_G1Q  = 1280,
  SO_G2   = 1344, SO_G2Q  = 1360,
  STATS_FLOATS = 2048
};

// ---- buffer offsets (floats) ----
// y1 bf16 [E][20][64] (2.62M fl) aliased by y3 bf16 [E][20][256] (10.49M fl)
static constexpr size_t F_Y13  = 2048;
static constexpr size_t F_Y2   = F_Y13 + 10485760;     // y2 bf16 [E][20][128] (5.24M fl)
static constexpr size_t F_POOL = F_Y2 + 5242880;       // (unused slack)
static constexpr size_t F_FCB  = F_POOL + 1048576;     // E*16 (fc out, later z2 of edgeconv)
static constexpr size_t F_EF   = F_FCB + 65536;        // E*16
static constexpr size_t F_PROJ = F_EF + 65536;         // 1024*16
static constexpr size_t F_Z1EC = F_PROJ + 16384;       // E*64
static constexpr size_t F_Z2T  = F_Z1EC + 262144;      // 3 x E*16 raw z2 (etype/elen/econv)
static constexpr size_t F_EDGEF= F_Z2T + 196608;       // 4*1025*16
static constexpr size_t F_WT2  = F_EDGEF + 65600;      // 128*192 bf16
static constexpr size_t F_WT3  = F_WT2 + 12288;        // 256*384 bf16

__device__ __forceinline__ float waveSum(float v){
  #pragma unroll
  for(int o=32;o;o>>=1) v += __shfl_down(v,o);
  return v;
}

__device__ __forceinline__ ushort f2bf(float f){
  uint u = __float_as_uint(f);
  uint r = (u + 0x7FFF + ((u>>16)&1)) >> 16;
  return (ushort)r;
}
__device__ __forceinline__ float bf2f(ushort u){
  return __uint_as_float(((uint)u)<<16);
}

// ---------------- scalar stats of angle & centroid ----------------
__global__ __launch_bounds__(256) void k_scalar_stats(const float* __restrict__ ang,
    const float* __restrict__ cen, float* __restrict__ st){
  int tid = blockIdx.x*256 + threadIdx.x;
  float sa=0, qa=0, sc=0, qc=0;
  for(int i=tid; i<M_PAIR; i += gridDim.x*256){
    float a=ang[i], c=cen[i];
    sa+=a; qa+=a*a; sc+=c; qc+=c*c;
  }
  __shared__ float red[4][4];
  int lane=threadIdx.x&63, wid=threadIdx.x>>6;
  sa=waveSum(sa); qa=waveSum(qa); sc=waveSum(sc); qc=waveSum(qc);
  if(lane==0){ red[wid][0]=sa; red[wid][1]=qa; red[wid][2]=sc; red[wid][3]=qc; }
  __syncthreads();
  if(threadIdx.x<4){
    float t=red[0][threadIdx.x]+red[1][threadIdx.x]+red[2][threadIdx.x]+red[3][threadIdx.x];
    atomicAdd(&st[threadIdx.x], t);
  }
}

// ------- layer-2 stats for angle (blocks 0..127) and centroid (128..255) -------
__global__ __launch_bounds__(256) void k_acl2(const float* __restrict__ ang,
    const float* __restrict__ cen,
    const float* __restrict__ angW1, const float* __restrict__ angW2,
    const float* __restrict__ cenW1, const float* __restrict__ cenW2,
    float* __restrict__ st){
  int half = blockIdx.x>>7;
  int bid  = blockIdx.x&127;
  const float* x  = half? cen  : ang;
  const float* W1 = half? cenW1: angW1;
  const float* W2 = half? cenW2: angW2;
  int soX = half? SO_CENX : SO_ANGX;
  int soS = half? SO_CEN2 : SO_ANG2;
  int soQ = half? SO_CEN2Q: SO_ANG2Q;
  __shared__ float w2s[256];
  __shared__ float Ah[16];
  __shared__ float mu_s, var_s;
  int tid=threadIdx.x;
  w2s[tid]=W2[tid];
  if(tid==0){
    float s=st[soX], qq=st[soX+1];
    float mu=s*(1.0f/262144.0f);
    float v=qq*(1.0f/262144.0f)-mu*mu; if(v<0)v=0;
    mu_s=mu; var_s=v;
  }
  __syncthreads();
  if(tid<16){ float w=W1[tid]; Ah[tid]=w/sqrtf(var_s*w*w+EPSB); }
  __syncthreads();
  float s[16], q[16];
  #pragma unroll
  for(int k=0;k<16;k++){ s[k]=0; q[k]=0; }
  for(int i=bid*256+tid; i<M_PAIR; i+=128*256){
    float xc=x[i]-mu_s;
    float h1[16];
    #pragma unroll
    for(int h=0;h<16;h++){ float t=xc*Ah[h]; h1[h]=t>0?t:0; }
    #pragma unroll
    for(int k=0;k<16;k++){
      float z=0;
      #pragma unroll
      for(int h=0;h<16;h++) z+=w2s[k*16+h]*h1[h];
      s[k]+=z; q[k]+=z*z;
    }
  }
  __shared__ float red[4][32];
  int lane=tid&63, wid=tid>>6;
  #pragma unroll
  for(int k=0;k<16;k++){
    float rs=waveSum(s[k]), rq=waveSum(q[k]);
    if(lane==0){ red[wid][k]=rs; red[wid][16+k]=rq; }
  }
  __syncthreads();
  if(tid<32){
    float t=red[0][tid]+red[1][tid]+red[2][tid]+red[3][tid];
    atomicAdd(&st[tid<16 ? soS+tid : soQ+(tid-16)], t);
  }
}

// -------- weight prep: pack conv weights to MFMA-fragment order --------
__global__ __launch_bounds__(256) void k_wprep(const float* __restrict__ c2w,
    const float* __restrict__ c3w, ushort* __restrict__ wt2, ushort* __restrict__ wt3){
  int t = blockIdx.x*256 + threadIdx.x;
  if(t < 128*192){
    int idx=t;
    int j=idx&7, lane=(idx>>3)&63, ks=(idx>>9)%6, ct=idx/3072;
    int l16=lane&15, lhi=lane>>4;
    int o=ct*16+l16, tap=ks/2, c=(ks%2)*32+lhi*8+j;
    wt2[idx]=f2bf(c2w[(o*64+c)*3+tap]);
  } else {
    int idx=t-128*192;
    if(idx<256*384){
      int j=idx&7, lane=(idx>>3)&63, ks=(idx>>9)%12, ct=idx/6144;
      int l16=lane&15, lhi=lane>>4;
      int o=ct*16+l16, tap=ks/4, c=(ks%4)*32+lhi*8+j;
      wt3[idx]=f2bf(c3w[(o*128+c)*3+tap]);
    }
  }
}

// ---------------- conv1: [E,12,20] -> y1 bf16 [E][20][64] + stats ----------------
__global__ __launch_bounds__(256) void k_conv1(const float* __restrict__ ed,
    const float* __restrict__ w, float* __restrict__ ws){
  __shared__ float wsh[64*36];
  __shared__ float xs[16][12][20];
  __shared__ float reds[4][64], redq[4][64];
  int tid=threadIdx.x;
  for(int i=tid;i<64*36;i+=256) wsh[i]=w[i];
  int e0=blockIdx.x*16;
  for(int i=tid;i<16*240;i+=256){
    int e=i/240, r=i%240, l=r/12, c=r%12;
    xs[e][c][l]=ed[(size_t)(e0+e)*240+r];
  }
  __syncthreads();
  int o=tid&63, eg=tid>>6;
  ushort* y1=(ushort*)(ws+F_Y13);
  float ssum=0, ssq=0;
  for(int ee=0;ee<4;ee++){
    int e=eg*4+ee;
    float acc[20];
    #pragma unroll
    for(int l=0;l<20;l++) acc[l]=0;
    for(int c=0;c<12;c++){
      float w0=wsh[o*36+c*3], w1=wsh[o*36+c*3+1], w2=wsh[o*36+c*3+2];
      const float* xr=xs[e][c];
      #pragma unroll
      for(int l=0;l<20;l++){
        acc[l]=fmaf(w1,xr[l],acc[l]);
        if(l>0)  acc[l]=fmaf(w0,xr[l-1],acc[l]);
        if(l<19) acc[l]=fmaf(w2,xr[l+1],acc[l]);
      }
    }
    size_t base=((size_t)(e0+e)*20)*64;
    #pragma unroll
    for(int l=0;l<20;l++){
      y1[base+(size_t)l*64+o]=f2bf(acc[l]);
      ssum+=acc[l]; ssq+=acc[l]*acc[l];
    }
  }
  reds[eg][o]=ssum; redq[eg][o]=ssq;
  __syncthreads();
  if(tid<64){
    float s=reds[0][tid]+reds[1][tid]+reds[2][tid]+reds[3][tid];
    atomicAdd(&ws[SO_C1+tid], s);
  } else if(tid<128){
    int oo=tid-64;
    float q=redq[0][oo]+redq[1][oo]+redq[2][oo]+redq[3][oo];
    atomicAdd(&ws[SO_C1Q+oo], q);
  }
}

// ---------------- MFMA conv (conv2/conv3): bn+lrelu(yin bf16) conv w -> yout bf16 ----
template<int CIN, int OUT, int EPB>
__global__ __launch_bounds__(256) void k_convmf(
    const ushort* __restrict__ yin, const ushort* __restrict__ wt,
    ushort* __restrict__ yout, float* __restrict__ ws,
    int soIn, int soInQ, int soOut, int soOutQ)
{
  constexpr int K = CIN*3;
  constexpr int KSTEPS = K/32;
  constexpr int M = EPB*20;
  constexpr int ROWT = M/16;
  constexpr int WCOLT = OUT/64;
  constexpr int ROWS = EPB*22;
  constexpr int RB = CIN*2;
  constexpr uint SWZ = RB/16 - 1;
  __shared__ ushort xs[ROWS*CIN];
  __shared__ float mi[CIN][2];
  int tid = threadIdx.x;
  for(int c=tid; c<CIN; c+=256){
    float m=ws[soIn+c]*(1.0f/81920.0f);
    float v=ws[soInQ+c]*(1.0f/81920.0f)-m*m; if(v<0)v=0;
    mi[c][0]=m; mi[c][1]=rsqrtf(v+EPSB);
  }
  uint* xs32 = (uint*)xs;
  for(int i=tid; i<EPB*2*(CIN/2); i+=256){
    int e=i/(CIN), r=i%(CIN); int lp = (r < CIN/2)? 0:21; int cw = r%(CIN/2);
    xs32[(e*22+lp)*(CIN/2)+cw]=0;
  }
  __syncthreads();
  int e0 = blockIdx.x*EPB;
  const ushort* src = yin + (size_t)e0*20*CIN;
  for(int i=tid; i<EPB*20*(CIN/8); i+=256){
    int c8 = i%(CIN/8); int rl = i/(CIN/8);
    int c = c8*8;
    short8 v = *(const short8*)(src + (size_t)rl*CIN + c);
    uint pk[4];
    #pragma unroll
    for(int jj=0;jj<4;jj++){
      float f0 = bf2f((ushort)v[jj*2]);
      float f1 = bf2f((ushort)v[jj*2+1]);
      f0=(f0-mi[c+jj*2  ][0])*mi[c+jj*2  ][1]; f0= f0>=0?f0:0.01f*f0;
      f1=(f1-mi[c+jj*2+1][0])*mi[c+jj*2+1][1]; f1= f1>=0?f1:0.01f*f1;
      pk[jj] = (uint)f2bf(f0) | ((uint)f2bf(f1)<<16);
    }
    int e = rl/20, l=rl%20;
    int row = e*22 + l + 1;
    uint byteoff = (uint)row*RB + (((uint)c*2) ^ (uint)((row&SWZ)<<4));
    *(uint4*)((char*)xs + byteoff) = make_uint4(pk[0],pk[1],pk[2],pk[3]);
  }
  __syncthreads();

  int lane = tid&63, wid = tid>>6;
  int l16 = lane&15, lhi = lane>>4;
  int colbase = wid*(OUT/4);
  f32x4 acc[ROWT][WCOLT];
  #pragma unroll
  for(int m=0;m<ROWT;m++)
    #pragma unroll
    for(int n=0;n<WCOLT;n++) acc[m][n]=(f32x4){0,0,0,0};
  int rowc[ROWT];
  #pragma unroll
  for(int m=0;m<ROWT;m++){ int r=m*16+l16; rowc[m]=(r/20)*22 + (r%20); }
  const ushort* wptile[WCOLT];
  #pragma unroll
  for(int n=0;n<WCOLT;n++)
    wptile[n] = wt + ((size_t)(wid*WCOLT + n)*KSTEPS)*512 + (size_t)lane*8;

  short8 aF0[ROWT], bF0[WCOLT], aF1[ROWT], bF1[WCOLT];

#define LOADK(ksv, A, B) { \
    int t_=(ksv)/(CIN/32); int c0_=((ksv)%(CIN/32))*32 + lhi*8; \
    _Pragma("unroll") \
    for(int m=0;m<ROWT;m++){ \
      int row_=rowc[m]+t_; \
      uint off_=(uint)row_*RB + (((uint)c0_*2) ^ (uint)((row_&SWZ)<<4)); \
      A[m]=*(const short8*)((char*)xs+off_); } \
    _Pragma("unroll") \
    for(int n=0;n<WCOLT;n++) B[n]=*(const short8*)(wptile[n]+(ksv)*512); }

#define MFMAK(A, B) { \
    _Pragma("unroll") \
    for(int m=0;m<ROWT;m++) \
      _Pragma("unroll") \
      for(int n=0;n<WCOLT;n++) \
        acc[m][n]=__builtin_amdgcn_mfma_f32_16x16x32_bf16(A[m],B[n],acc[m][n],0,0,0); }

  LOADK(0, aF0, bF0);
  #pragma unroll
  for(int kp=0; kp<KSTEPS/2; kp++){
    int ks = kp*2;
    LOADK(ks+1, aF1, bF1);
    MFMAK(aF0, bF0);
    if(ks+2<KSTEPS) LOADK(ks+2, aF0, bF0);
    MFMAK(aF1, bF1);
  }
#undef LOADK
#undef MFMAK

  #pragma unroll
  for(int n=0;n<WCOLT;n++){
    float s=0,q=0;
    #pragma unroll
    for(int m=0;m<ROWT;m++)
      #pragma unroll
      for(int j=0;j<4;j++){ float a=acc[m][n][j]; s+=a; q+=a*a; }
    s += __shfl_xor(s,16); s += __shfl_xor(s,32);
    q += __shfl_xor(q,16); q += __shfl_xor(q,32);
    if(lhi==0){
      int o = colbase+n*16+l16;
      atomicAdd(&ws[soOut+o], s);
      atomicAdd(&ws[soOutQ+o], q);
    }
  }
  ushort* dst = yout + (size_t)blockIdx.x*M*OUT;
  #pragma unroll
  for(int m=0;m<ROWT;m++)
    #pragma unroll
    for(int j=0;j<4;j++){
      int R = m*16 + lhi*4 + j;
      #pragma unroll
      for(int n=0;n<WCOLT;n++)
        dst[(size_t)R*OUT + colbase + n*16 + l16] = f2bf(acc[m][n][j]);
    }
}

// -------- fused pool+fc: mean_l lrelu(bn(y3 bf16)) -> fc -> fcb [E,16] + stats --------
__global__ __launch_bounds__(256) void k_poolfc(const float* __restrict__ fcw, float* __restrict__ ws){
  __shared__ float ps[16][260];
  __shared__ float red[4][32];
  __shared__ float mo[256][2];
  int tid=threadIdx.x;
  {
    float m=ws[SO_C3+tid]*(1.0f/81920.0f);
    float v=ws[SO_C3Q+tid]*(1.0f/81920.0f)-m*m; if(v<0)v=0;
    mo[tid][0]=m; mo[tid][1]=rsqrtf(v+EPSB);
  }
  __syncthreads();
  int e0=blockIdx.x*16;
  const ushort* y3=(const ushort*)(ws+F_Y13);
  float m=mo[tid][0], inv=mo[tid][1];
  for(int el=0;el<16;el++){
    const ushort* row=y3+((size_t)(e0+el)*20)*256+tid;
    float s=0;
    #pragma unroll
    for(int l=0;l<20;l++){
      float x=(bf2f(row[(size_t)l*256])-m)*inv;
      s += x>=0.f? x : 0.01f*x;
    }
    ps[el][tid]=s*(1.0f/20.0f);
  }
  __syncthreads();
  int e=tid>>4, h=tid&15;
  const float* wr=fcw+(size_t)h*256;
  float z=0;
  for(int c=0;c<256;c++) z+=ps[e][c]*wr[c];
  ws[F_FCB+(size_t)(e0+e)*16+h]=z;
  float s=z, q=z*z;
  #pragma unroll
  for(int o=16;o<64;o<<=1){ s+=__shfl_down(s,o); q+=__shfl_down(q,o); }
  int lane=tid&63, wid=tid>>6;
  if(lane<16){ red[wid][lane]=s; red[wid][16+lane]=q; }
  __syncthreads();
  if(tid<32){
    float v=red[0][tid]+red[1][tid]+red[2][tid]+red[3][tid];
    atomicAdd(&ws[tid<16? SO_FC+tid : SO_FCQ+(tid-16)], v);
  }
}

// -------- one-block small MLP: l1 stats + l2 raw z2 + l2 stats, no atomics --------
template<int DIM>
__device__ __forceinline__ void small_mlp_block(const float* __restrict__ x,
    const float* __restrict__ W1, const float* __restrict__ W2,
    float* __restrict__ ws, int so2, int so2q, float* __restrict__ z2out){
  __shared__ float w1s[176];
  __shared__ float w2s[256];
  __shared__ float red[16][32];
  __shared__ float st32[32];
  __shared__ float mi1[16][2];
  int tid=threadIdx.x, lane=tid&63, wid=tid>>6;
  if(tid<16*DIM) w1s[tid]=W1[tid];
  if(tid>=256 && tid<512) w2s[tid-256]=W2[tid-256];
  __syncthreads();
  float s[16], q[16];
  #pragma unroll
  for(int k=0;k<16;k++){ s[k]=0; q[k]=0; }
  #pragma unroll
  for(int ee=0;ee<4;ee++){
    int e=ee*1024+tid;
    float xv[DIM];
    #pragma unroll
    for(int j=0;j<DIM;j++) xv[j]=x[(size_t)e*DIM+j];
    #pragma unroll
    for(int h=0;h<16;h++){
      float z=0;
      #pragma unroll
      for(int j=0;j<DIM;j++) z+=w1s[h*DIM+j]*xv[j];
      s[h]+=z; q[h]+=z*z;
    }
  }
  #pragma unroll
  for(int k=0;k<16;k++){
    float rs=waveSum(s[k]), rq=waveSum(q[k]);
    if(lane==0){ red[wid][k]=rs; red[wid][16+k]=rq; }
  }
  __syncthreads();
  if(tid<32){
    float t=0;
    #pragma unroll
    for(int w=0;w<16;w++) t+=red[w][tid];
    st32[tid]=t;
  }
  __syncthreads();
  if(tid<16){
    float m=st32[tid]*(1.0f/4096.0f);
    float v=st32[16+tid]*(1.0f/4096.0f)-m*m; if(v<0)v=0;
    mi1[tid][0]=m; mi1[tid][1]=rsqrtf(v+EPSB);
  }
  __syncthreads();
  #pragma unroll
  for(int k=0;k<16;k++){ s[k]=0; q[k]=0; }
  #pragma unroll
  for(int ee=0;ee<4;ee++){
    int e=ee*1024+tid;
    float xv[DIM];
    #pragma unroll
    for(int j=0;j<DIM;j++) xv[j]=x[(size_t)e*DIM+j];
    float h1[16];
    #pragma unroll
    for(int h=0;h<16;h++){
      float z=0;
      #pragma unroll
      for(int j=0;j<DIM;j++) z+=w1s[h*DIM+j]*xv[j];
      z=(z-mi1[h][0])*mi1[h][1];
      h1[h]=z>0?z:0;
    }
    #pragma unroll
    for(int k=0;k<16;k++){
      float z=0;
      #pragma unroll
      for(int h=0;h<16;h++) z+=w2s[k*16+h]*h1[h];
      z2out[(size_t)e*16+k]=z;
      s[k]+=z; q[k]+=z*z;
    }
  }
  __syncthreads();
  #pragma unroll
  for(int k=0;k<16;k++){
    float rs=waveSum(s[k]), rq=waveSum(q[k]);
    if(lane==0){ red[wid][k]=rs; red[wid][16+k]=rq; }
  }
  __syncthreads();
  if(tid<32){
    float t=0;
    #pragma unroll
    for(int w=0;w<16;w++) t+=red[w][tid];
    ws[tid<16? so2+tid : so2q+(tid-16)]=t;
  }
}

__global__ __launch_bounds__(1024) void k_small3(
    const float* __restrict__ et, const float* __restrict__ el, const float* __restrict__ ev,
    const float* __restrict__ etW1, const float* __restrict__ etW2,
    const float* __restrict__ elW1, const float* __restrict__ elW2,
    const float* __restrict__ evW1, const float* __restrict__ evW2,
    float* __restrict__ ws){
  if(blockIdx.x==0)      small_mlp_block<11>(et,etW1,etW2,ws,SO_ET2,SO_ET2Q,ws+F_Z2T);
  else if(blockIdx.x==1) small_mlp_block<1> (el,elW1,elW2,ws,SO_EL2,SO_EL2Q,ws+F_Z2T+65536);
  else                   small_mlp_block<3> (ev,evW1,evW2,ws,SO_EV2,SO_EV2Q,ws+F_Z2T+131072);
}

// ---------------- ef assembly: BN-apply stored z2s + fc-bn -> ef [E,16] ----------------
__device__ __constant__ int EF_BASES[4][2] = {
  {SO_ET2,SO_ET2Q},{SO_EL2,SO_EL2Q},{SO_EV2,SO_EV2Q},{SO_FC,SO_FCQ}
};

__global__ __launch_bounds__(256) void k_ef(float* __restrict__ ws){
  __shared__ float mi[4][16][2];
  int tid=threadIdx.x;
  if(tid<64){
    int g=tid>>4, h=tid&15;
    float m=ws[EF_BASES[g][0]+h]*(1.0f/4096.0f);
    float v=ws[EF_BASES[g][1]+h]*(1.0f/4096.0f)-m*m; if(v<0)v=0;
    mi[g][h][0]=m; mi[g][h][1]=rsqrtf(v+EPSB);
  }
  __syncthreads();
  int e=blockIdx.x*256+tid;
  float acc[16];
  #pragma unroll
  for(int h=0;h<16;h++){
    float z=ws[F_FCB+(size_t)e*16+h];
    acc[h]=(z-mi[3][h][0])*mi[3][h][1];   // fc: BN, no relu
  }
  #pragma unroll
  for(int g=0;g<3;g++){
    const float* z2=ws+F_Z2T+(size_t)g*65536;
    #pragma unroll
    for(int k=0;k<16;k++){
      float z=z2[(size_t)e*16+k];
      float r=(z-mi[g][k][0])*mi[g][k][1];
      acc[k]+= r>0?r:0;
    }
  }
  #pragma unroll
  for(int h=0;h<16;h++) ws[F_EF+(size_t)e*16+h]=acc[h];
}

// ---------------- proj: node_feat @ ec_Wp.T -> proj [1024,16] ----------------
__global__ __launch_bounds__(256) void k_proj(const float* __restrict__ nf,
    const float* __restrict__ Wp, float* __restrict__ ws){
  __shared__ float wps[4096];
  int tid=threadIdx.x;
  for(int i=tid;i<4096;i+=256) wps[i]=Wp[i];
  __syncthreads();
  int t=blockIdx.x*256+tid;
  int v=t>>4, h=t&15;
  const float* row=nf+(size_t)v*256;
  const float* wr=wps+h*256;
  float z=0;
  for(int c=0;c<256;c++) z+=row[c]*wr[c];
  ws[F_PROJ+t]=z;
}

// ---------------- agg + edgeconv layer1 -> z1ec [E,64] + stats ----------------
__global__ __launch_bounds__(256) void k_agg(const int* __restrict__ src, const int* __restrict__ dst,
    const float* __restrict__ ecW1, float* __restrict__ ws){
  __shared__ float w1s[1024];
  int tid=threadIdx.x;
  for(int i=tid;i<1024;i+=256) w1s[i]=ecW1[i];
  __syncthreads();
  int e=blockIdx.x*256+tid;
  int s=src[e], d=dst[e];
  float a[16];
  #pragma unroll
  for(int h=0;h<16;h++)
    a[h]=ws[F_EF+(size_t)e*16+h]+ws[F_PROJ+(size_t)s*16+h]+ws[F_PROJ+(size_t)d*16+h];
  int lane=tid&63;
  for(int o=0;o<64;o++){
    float z=0;
    #pragma unroll
    for(int h=0;h<16;h++) z+=w1s[o*16+h]*a[h];
    ws[F_Z1EC+(size_t)e*64+o]=z;
    float rs=waveSum(z), rq=waveSum(z*z);
    if(lane==0){ atomicAdd(&ws[SO_G1+o],rs); atomicAdd(&ws[SO_G1Q+o],rq); }
  }
}

// ---------------- edgeconv layer2 -> z2 [E,16] (in F_FCB) + stats ----------------
__global__ __launch_bounds__(256) void k_ec2(const float* __restrict__ ecW2, float* __restrict__ ws){
  __shared__ float w2s[1024];
  __shared__ float mi[64][2];
  __shared__ float red[4][32];
  int tid=threadIdx.x;
  for(int i=tid;i<1024;i+=256) w2s[i]=ecW2[i];
  if(tid<64){
    float m=ws[SO_G1+tid]*(1.0f/4096.0f);
    float v=ws[SO_G1Q+tid]*(1.0f/4096.0f)-m*m; if(v<0)v=0;
    mi[tid][0]=m; mi[tid][1]=rsqrtf(v+EPSB);
  }
  __syncthreads();
  int e=blockIdx.x*256+tid;
  float acc[16];
  #pragma unroll
  for(int k=0;k<16;k++) acc[k]=0;
  for(int o=0;o<64;o++){
    float z=ws[F_Z1EC+(size_t)e*64+o];
    float h=(z-mi[o][0])*mi[o][1];
    h=h>0?h:0;
    #pragma unroll
    for(int k=0;k<16;k++) acc[k]+=w2s[k*64+o]*h;
  }
  float s[16], q[16];
  #pragma unroll
  for(int k=0;k<16;k++){
    ws[F_FCB+(size_t)e*16+k]=acc[k];
    s[k]=acc[k]; q[k]=acc[k]*acc[k];
  }
  int lane=tid&63, wid=tid>>6;
  #pragma unroll
  for(int k=0;k<16;k++){
    float rs=waveSum(s[k]), rq=waveSum(q[k]);
    if(lane==0){ red[wid][k]=rs; red[wid][16+k]=rq; }
  }
  __syncthreads();
  if(tid<32){
    float t=red[0][tid]+red[1][tid]+red[2][tid]+red[3][tid];
    atomicAdd(&ws[tid<16 ? SO_G2+tid : SO_G2Q+(tid-16)], t);
  }
}

// ---------------- edge_feature fill [4,1025,16] ----------------
__global__ __launch_bounds__(256) void k_ef2(float* __restrict__ ws){
  int t=blockIdx.x*256+threadIdx.x;
  if(t>=4*1025*16) return;
  int h=t&15, r=t>>4;
  int b=r/1025, pos=r%1025;
  float v=0;
  if(pos<1024){
    int e=b*1024+pos;
    float z=ws[F_FCB+(size_t)e*16+h];
    float m=ws[SO_G2+h]*(1.0f/4096.0f);
    float va=ws[SO_G2Q+h]*(1.0f/4096.0f)-m*m; if(va<0)va=0;
    v=(z-m)*rsqrtf(va+EPSB);
    v=v>0?v:0;
  }
  ws[F_EDGEF+t]=v;
}

// ---------------- main per-pair kernel: interior output ----------------
__global__ __launch_bounds__(256) void k_pair(const float* __restrict__ ab,
    const int* __restrict__ sd, const float* __restrict__ ang, const float* __restrict__ cen,
    const int* __restrict__ ep, const float* __restrict__ sdemb, const float* __restrict__ edisw,
    const float* __restrict__ angW1, const float* __restrict__ angW2,
    const float* __restrict__ cenW1, const float* __restrict__ cenW2,
    const float* __restrict__ ws, float* __restrict__ out){
  __shared__ float wd[1280];
  __shared__ float w2a[256], w2c[256];
  __shared__ float Aa[16], Ac[16], m2a[16], i2a[16], m2c[16], i2c[16];
  __shared__ float muA, muC, varA, varC;
  int tid=threadIdx.x;
  for(int i=tid;i<1280;i+=256) wd[i]=edisw[i];
  w2a[tid]=angW2[tid]; w2c[tid]=cenW2[tid];
  if(tid==0){
    float s=ws[SO_ANGX], q=ws[SO_ANGX+1];
    float mu=s*(1.0f/262144.0f);
    float v=q*(1.0f/262144.0f)-mu*mu; if(v<0)v=0;
    muA=mu; varA=v;
    s=ws[SO_CENX]; q=ws[SO_CENX+1];
    mu=s*(1.0f/262144.0f);
    v=q*(1.0f/262144.0f)-mu*mu; if(v<0)v=0;
    muC=mu; varC=v;
  }
  __syncthreads();
  if(tid<16){
    float w=angW1[tid]; Aa[tid]=w/sqrtf(varA*w*w+EPSB);
    float m=ws[SO_ANG2+tid]*(1.0f/262144.0f);
    float v=ws[SO_ANG2Q+tid]*(1.0f/262144.0f)-m*m; if(v<0)v=0;
    m2a[tid]=m; i2a[tid]=rsqrtf(v+EPSB);
  } else if(tid<32){
    int h=tid-16;
    float w=cenW1[h]; Ac[h]=w/sqrtf(varC*w*w+EPSB);
    float m=ws[SO_CEN2+h]*(1.0f/262144.0f);
    float v=ws[SO_CEN2Q+h]*(1.0f/262144.0f)-m*m; if(v<0)v=0;
    m2c[h]=m; i2c[h]=rsqrtf(v+EPSB);
  }
  __syncthreads();
  int t=blockIdx.x*256+tid;            // b,i,j
  int b=t>>16, rem=t&65535, i=rem>>8, j=rem&255;
  int sdv=sd[t];
  float xa=ang[t], xc0=cen[t];
  float acc[16];
  const float* se=sdemb+(size_t)sdv*16;
  #pragma unroll
  for(int k=0;k<16;k++) acc[k]=se[k];
  { // angle MLP
    float xc=xa-muA;
    float h1[16];
    #pragma unroll
    for(int h=0;h<16;h++){ float v=xc*Aa[h]; h1[h]=v>0?v:0; }
    #pragma unroll
    for(int k=0;k<16;k++){
      float z=0;
      #pragma unroll
      for(int h=0;h<16;h++) z+=w2a[k*16+h]*h1[h];
      float r=(z-m2a[k])*i2a[k];
      acc[k]+= r>0?r:0;
    }
  }
  { // centroid MLP
    float xc=xc0-muC;
    float h1[16];
    #pragma unroll
    for(int h=0;h<16;h++){ float v=xc*Ac[h]; h1[h]=v>0?v:0; }
    #pragma unroll
    for(int k=0;k<16;k++){
      float z=0;
      #pragma unroll
      for(int h=0;h<16;h++) z+=w2c[k*16+h]*h1[h];
      float r=(z-m2c[k])*i2c[k];
      acc[k]+= r>0?r:0;
    }
  }
  { // multi-hop edge bias
    int sdm = sdv==0 ? 1 : sdv;
    if(sdm>1) sdm-=1;
    if(sdm>5) sdm=5;
    float inv=1.0f/((float)sdm+1e-6f);
    float eb[16];
    #pragma unroll
    for(int k=0;k<16;k++) eb[k]=0;
    const float* EF=ws+F_EDGEF+(size_t)b*1025*16;
    #pragma unroll
    for(int d=0;d<5;d++){
      int idx=ep[(size_t)t*5+d];
      const float* r=EF+(size_t)idx*16;
      float e16[16];
      #pragma unroll
      for(int k=0;k<16;k+=4){
        float4 v=*(const float4*)(r+k);
        e16[k]=v.x; e16[k+1]=v.y; e16[k+2]=v.z; e16[k+3]=v.w;
      }
      const float* wdd=wd+d*256;
      #pragma unroll
      for(int h=0;h<16;h++){
        float evv=e16[h];
        const float4* wv4=(const float4*)(wdd+h*16);
        #pragma unroll
        for(int k4=0;k4<4;k4++){
          float4 wv=wv4[k4];
          eb[k4*4+0]+=evv*wv.x; eb[k4*4+1]+=evv*wv.y;
          eb[k4*4+2]+=evv*wv.z; eb[k4*4+3]+=evv*wv.w;
        }
      }
    }
    #pragma unroll
    for(int k=0;k<16;k++) acc[k]+=eb[k]*inv;
  }
  float base2=2.0f*ab[(size_t)b*66049+(size_t)(i+1)*257+(j+1)];
  #pragma unroll
  for(int k=0;k<16;k++)
    out[(((size_t)b*16+k)*257+(i+1))*257+(j+1)]=acc[k]+base2;
}

// ---------------- borders: row 0 and col 0 ----------------
__global__ __launch_bounds__(256) void k_border(const float* __restrict__ ab,
    const float* __restrict__ virt, float* __restrict__ out){
  int t=blockIdx.x*256+threadIdx.x;
  if(t>=4*16*513) return;
  int idx=t%513, bh=t/513;
  int b=bh>>4, h=bh&15;
  float v=virt[h];
  if(idx<257){
    out[(((size_t)b*16+h)*257)*257+idx]=2.0f*ab[(size_t)b*66049+idx]+v;
  } else {
    int p=idx-256;   // 1..256
    out[(((size_t)b*16+h)*257+p)*257]=2.0f*ab[(size_t)b*66049+(size_t)p*257]+v;
  }
}

extern "C" void kernel_launch(void* const* d_in, const int* in_sizes, int n_in,
                              void* d_out, int out_size, void* d_ws, size_t ws_size,
                              hipStream_t stream) {
  const float* ab    =(const float*)d_in[0];
  const int*   sdist =(const int*)  d_in[1];
  const float* ang   =(const float*)d_in[2];
  const float* cen   =(const float*)d_in[3];
  const int*   ep    =(const int*)  d_in[4];
  const float* edata =(const float*)d_in[5];
  const float* etype =(const float*)d_in[6];
  const float* elen  =(const float*)d_in[7];
  const float* econv =(const float*)d_in[8];
  const int*   src   =(const int*)  d_in[10];
  const int*   dst   =(const int*)  d_in[11];
  const float* nf    =(const float*)d_in[12];
  const float* sdemb =(const float*)d_in[13];
  const float* virt  =(const float*)d_in[14];
  const float* angW1 =(const float*)d_in[15];
  const float* angW2 =(const float*)d_in[16];
  const float* cenW1 =(const float*)d_in[17];
  const float* cenW2 =(const float*)d_in[18];
  const float* etW1  =(const float*)d_in[19];
  const float* etW2  =(const float*)d_in[20];
  const float* elW1  =(const float*)d_in[21];
  const float* elW2  =(const float*)d_in[22];
  const float* evW1  =(const float*)d_in[23];
  const float* evW2  =(const float*)d_in[24];
  const float* c1w   =(const float*)d_in[25];
  const float* c2w   =(const float*)d_in[26];
  const float* c3w   =(const float*)d_in[27];
  const float* fcw   =(const float*)d_in[28];
  const float* edisw =(const float*)d_in[29];
  const float* ecWp  =(const float*)d_in[30];
  const float* ecW1  =(const float*)d_in[31];
  const float* ecW2  =(const float*)d_in[32];
  float* ws=(float*)d_ws;
  float* out=(float*)d_out;

  hipMemsetAsync(d_ws, 0, STATS_FLOATS*sizeof(float), stream);

  k_wprep<<<480,256,0,stream>>>(c2w,c3w,(ushort*)(ws+F_WT2),(ushort*)(ws+F_WT3));

  k_scalar_stats<<<256,256,0,stream>>>(ang,cen,ws);
  k_acl2<<<256,256,0,stream>>>(ang,cen,angW1,angW2,cenW1,cenW2,ws);

  k_conv1<<<256,256,0,stream>>>(edata,c1w,ws);
  k_convmf<64,128,8><<<512,256,0,stream>>>((const ushort*)(ws+F_Y13),(const ushort*)(ws+F_WT2),
                                           (ushort*)(ws+F_Y2),ws,SO_C1,SO_C1Q,SO_C2,SO_C2Q);
  k_convmf<128,256,4><<<1024,256,0,stream>>>((const ushort*)(ws+F_Y2),(const ushort*)(ws+F_WT3),
                                             (ushort*)(ws+F_Y13),ws,SO_C2,SO_C2Q,SO_C3,SO_C3Q);
  k_poolfc<<<256,256,0,stream>>>(fcw,ws);

  k_small3<<<3,1024,0,stream>>>(etype,elen,econv,etW1,etW2,elW1,elW2,evW1,evW2,ws);

  k_ef<<<16,256,0,stream>>>(ws);
  k_proj<<<64,256,0,stream>>>(nf,ecWp,ws);
  k_agg<<<16,256,0,stream>>>(src,dst,ecW1,ws);
  k_ec2<<<16,256,0,stream>>>(ecW2,ws);
  k_ef2<<<257,256,0,stream>>>(ws);

  k_pair<<<1024,256,0,stream>>>(ab,sdist,ang,cen,ep,sdemb,edisw,angW1,angW2,cenW1,cenW2,ws,out);
  k_border<<<129,256,0,stream>>>(ab,virt,out);
}

// Round 6
// 287.199 us; speedup vs baseline: 1.4070x; 1.4070x over previous
//
#include <hip/hip_runtime.h>

#define EPSB 1e-5f
#define B_ 4
#define N_ 256
#define H_ 16
#define D_ 5
#define E_ 4096
#define M_PAIR (B_*N_*N_)   // 262144

typedef __attribute__((ext_vector_type(8))) short short8;
typedef __attribute__((ext_vector_type(4))) float f32x4;

// ---- stats slot offsets (floats) in ws ----
enum {
  SO_ANGX = 0,
  SO_CENX = 2,
  SO_ANG2 = 16,  SO_ANG2Q = 32,
  SO_CEN2 = 48,  SO_CEN2Q = 64,
  SO_C1   = 96,  SO_C1Q   = 160,
  SO_C2   = 224, SO_C2Q   = 352,
  SO_C3   = 480, SO_C3Q   = 736,
  SO_FC   = 992, SO_FCQ   = 1008,
  SO_ET1  = 1024, SO_ET1Q = 1040,
  SO_ET2  = 1056, SO_ET2Q = 1072,
  SO_EL1  = 1088, SO_EL1Q = 1104,
  SO_EL2  = 1120, SO_EL2Q = 1136,
  SO_EV1  = 1152, SO_EV1Q = 1168,
  SO_EV2  = 1184, SO_EV2Q = 1200,
  SO_G1   = 1216, SO_G1Q  = 1280,
  SO_G2   = 1344, SO_G2Q  = 1360,
  STATS_FLOATS = 2048
};

// ---- buffer offsets (floats) ----
// y1 bf16 [E][20][64] (aliased by y3 bf16 [E][20][256])
static constexpr size_t F_Y13  = 2048;
static constexpr size_t F_Y2   = F_Y13 + 10485760;     // y2 bf16 [E][20][128]
static constexpr size_t F_POOL = F_Y2 + 5242880;       // (slack)
static constexpr size_t F_FCB  = F_POOL + 1048576;     // E*16 (fc out, later z2 of edgeconv)
static constexpr size_t F_EF   = F_FCB + 65536;        // E*16
static constexpr size_t F_PROJ = F_EF + 65536;         // 1024*16
static constexpr size_t F_Z1EC = F_PROJ + 16384;       // E*64
static constexpr size_t F_Z2T  = F_Z1EC + 262144;      // 3 x E*16 raw z2 (etype/elen/econv)
static constexpr size_t F_EDGEF= F_Z2T + 196608;       // 4*1025*16
static constexpr size_t F_WT2  = F_EDGEF + 65600;      // 128*192 bf16
static constexpr size_t F_WT3  = F_WT2 + 12288;        // 256*384 bf16

__device__ __forceinline__ float waveSum(float v){
  #pragma unroll
  for(int o=32;o;o>>=1) v += __shfl_down(v,o);
  return v;
}

__device__ __forceinline__ ushort f2bf(float f){
  uint u = __float_as_uint(f);
  uint r = (u + 0x7FFF + ((u>>16)&1)) >> 16;
  return (ushort)r;
}
__device__ __forceinline__ float bf2f(ushort u){
  return __uint_as_float(((uint)u)<<16);
}

// block = 256 threads (4 waves). Reduce 16 sums + 16 sumsqs, atomicAdd to ws.
__device__ __forceinline__ void red32_atomic(float* ws, int so, int soq, float* s, float* q){
  __shared__ float red[4][32];
  int tid=threadIdx.x, lane=tid&63, wid=tid>>6;
  #pragma unroll
  for(int k=0;k<16;k++){
    float rs=waveSum(s[k]), rq=waveSum(q[k]);
    if(lane==0){ red[wid][k]=rs; red[wid][16+k]=rq; }
  }
  __syncthreads();
  if(tid<32){
    float t=red[0][tid]+red[1][tid]+red[2][tid]+red[3][tid];
    atomicAdd(&ws[tid<16 ? so+tid : soq+(tid-16)], t);
  }
}

// ---------------- scalar stats of angle & centroid ----------------
__global__ __launch_bounds__(256) void k_scalar_stats(const float* __restrict__ ang,
    const float* __restrict__ cen, float* __restrict__ st){
  int tid = blockIdx.x*256 + threadIdx.x;
  float sa=0, qa=0, sc=0, qc=0;
  for(int i=tid; i<M_PAIR; i += gridDim.x*256){
    float a=ang[i], c=cen[i];
    sa+=a; qa+=a*a; sc+=c; qc+=c*c;
  }
  __shared__ float red[4][4];
  int lane=threadIdx.x&63, wid=threadIdx.x>>6;
  sa=waveSum(sa); qa=waveSum(qa); sc=waveSum(sc); qc=waveSum(qc);
  if(lane==0){ red[wid][0]=sa; red[wid][1]=qa; red[wid][2]=sc; red[wid][3]=qc; }
  __syncthreads();
  if(threadIdx.x<4){
    float t=red[0][threadIdx.x]+red[1][threadIdx.x]+red[2][threadIdx.x]+red[3][threadIdx.x];
    atomicAdd(&st[threadIdx.x], t);
  }
}

// ------- layer-2 stats for angle (blocks 0..127) and centroid (128..255) -------
__global__ __launch_bounds__(256) void k_acl2(const float* __restrict__ ang,
    const float* __restrict__ cen,
    const float* __restrict__ angW1, const float* __restrict__ angW2,
    const float* __restrict__ cenW1, const float* __restrict__ cenW2,
    float* __restrict__ st){
  int half = blockIdx.x>>7;
  int bid  = blockIdx.x&127;
  const float* x  = half? cen  : ang;
  const float* W1 = half? cenW1: angW1;
  const float* W2 = half? cenW2: angW2;
  int soX = half? SO_CENX : SO_ANGX;
  int soS = half? SO_CEN2 : SO_ANG2;
  int soQ = half? SO_CEN2Q: SO_ANG2Q;
  __shared__ float w2s[256];
  __shared__ float Ah[16];
  __shared__ float mu_s, var_s;
  int tid=threadIdx.x;
  w2s[tid]=W2[tid];
  if(tid==0){
    float s=st[soX], qq=st[soX+1];
    float mu=s*(1.0f/262144.0f);
    float v=qq*(1.0f/262144.0f)-mu*mu; if(v<0)v=0;
    mu_s=mu; var_s=v;
  }
  __syncthreads();
  if(tid<16){ float w=W1[tid]; Ah[tid]=w/sqrtf(var_s*w*w+EPSB); }
  __syncthreads();
  float s[16], q[16];
  #pragma unroll
  for(int k=0;k<16;k++){ s[k]=0; q[k]=0; }
  for(int i=bid*256+tid; i<M_PAIR; i+=128*256){
    float xc=x[i]-mu_s;
    float h1[16];
    #pragma unroll
    for(int h=0;h<16;h++){ float t=xc*Ah[h]; h1[h]=t>0?t:0; }
    #pragma unroll
    for(int k=0;k<16;k++){
      float z=0;
      #pragma unroll
      for(int h=0;h<16;h++) z+=w2s[k*16+h]*h1[h];
      s[k]+=z; q[k]+=z*z;
    }
  }
  red32_atomic(st, soS, soQ, s, q);
}

// -------- weight prep: pack conv weights to MFMA-fragment order --------
__global__ __launch_bounds__(256) void k_wprep(const float* __restrict__ c2w,
    const float* __restrict__ c3w, ushort* __restrict__ wt2, ushort* __restrict__ wt3){
  int t = blockIdx.x*256 + threadIdx.x;
  if(t < 128*192){
    int idx=t;
    int j=idx&7, lane=(idx>>3)&63, ks=(idx>>9)%6, ct=idx/3072;
    int l16=lane&15, lhi=lane>>4;
    int o=ct*16+l16, tap=ks/2, c=(ks%2)*32+lhi*8+j;
    wt2[idx]=f2bf(c2w[(o*64+c)*3+tap]);
  } else {
    int idx=t-128*192;
    if(idx<256*384){
      int j=idx&7, lane=(idx>>3)&63, ks=(idx>>9)%12, ct=idx/6144;
      int l16=lane&15, lhi=lane>>4;
      int o=ct*16+l16, tap=ks/4, c=(ks%4)*32+lhi*8+j;
      wt3[idx]=f2bf(c3w[(o*128+c)*3+tap]);
    }
  }
}

// ---------------- conv1: [E,12,20] -> y1 bf16 [E][20][64] + stats ----------------
__global__ __launch_bounds__(256) void k_conv1(const float* __restrict__ ed,
    const float* __restrict__ w, float* __restrict__ ws){
  __shared__ float wsh[64*36];
  __shared__ float xs[16][12][20];
  __shared__ float reds[4][64], redq[4][64];
  int tid=threadIdx.x;
  for(int i=tid;i<64*36;i+=256) wsh[i]=w[i];
  int e0=blockIdx.x*16;
  for(int i=tid;i<16*240;i+=256){
    int e=i/240, r=i%240, l=r/12, c=r%12;
    xs[e][c][l]=ed[(size_t)(e0+e)*240+r];
  }
  __syncthreads();
  int o=tid&63, eg=tid>>6;
  ushort* y1=(ushort*)(ws+F_Y13);
  float ssum=0, ssq=0;
  for(int ee=0;ee<4;ee++){
    int e=eg*4+ee;
    float acc[20];
    #pragma unroll
    for(int l=0;l<20;l++) acc[l]=0;
    for(int c=0;c<12;c++){
      float w0=wsh[o*36+c*3], w1=wsh[o*36+c*3+1], w2=wsh[o*36+c*3+2];
      const float* xr=xs[e][c];
      #pragma unroll
      for(int l=0;l<20;l++){
        acc[l]=fmaf(w1,xr[l],acc[l]);
        if(l>0)  acc[l]=fmaf(w0,xr[l-1],acc[l]);
        if(l<19) acc[l]=fmaf(w2,xr[l+1],acc[l]);
      }
    }
    size_t base=((size_t)(e0+e)*20)*64;
    #pragma unroll
    for(int l=0;l<20;l++){
      y1[base+(size_t)l*64+o]=f2bf(acc[l]);
      ssum+=acc[l]; ssq+=acc[l]*acc[l];
    }
  }
  reds[eg][o]=ssum; redq[eg][o]=ssq;
  __syncthreads();
  if(tid<64){
    float s=reds[0][tid]+reds[1][tid]+reds[2][tid]+reds[3][tid];
    atomicAdd(&ws[SO_C1+tid], s);
  } else if(tid<128){
    int oo=tid-64;
    float q=redq[0][oo]+redq[1][oo]+redq[2][oo]+redq[3][oo];
    atomicAdd(&ws[SO_C1Q+oo], q);
  }
}

// ---------------- MFMA conv (conv2/conv3): bn+lrelu(yin bf16) conv w -> yout bf16 ----
template<int CIN, int OUT, int EPB>
__global__ __launch_bounds__(256) void k_convmf(
    const ushort* __restrict__ yin, const ushort* __restrict__ wt,
    ushort* __restrict__ yout, float* __restrict__ ws,
    int soIn, int soInQ, int soOut, int soOutQ)
{
  constexpr int K = CIN*3;
  constexpr int KSTEPS = K/32;
  constexpr int M = EPB*20;
  constexpr int ROWT = M/16;
  constexpr int WCOLT = OUT/64;
  constexpr int ROWS = EPB*22;
  constexpr int RB = CIN*2;
  constexpr uint SWZ = RB/16 - 1;
  __shared__ ushort xs[ROWS*CIN];
  __shared__ float mi[CIN][2];
  int tid = threadIdx.x;
  for(int c=tid; c<CIN; c+=256){
    float m=ws[soIn+c]*(1.0f/81920.0f);
    float v=ws[soInQ+c]*(1.0f/81920.0f)-m*m; if(v<0)v=0;
    mi[c][0]=m; mi[c][1]=rsqrtf(v+EPSB);
  }
  uint* xs32 = (uint*)xs;
  for(int i=tid; i<EPB*2*(CIN/2); i+=256){
    int e=i/(CIN), r=i%(CIN); int lp = (r < CIN/2)? 0:21; int cw = r%(CIN/2);
    xs32[(e*22+lp)*(CIN/2)+cw]=0;
  }
  __syncthreads();
  int e0 = blockIdx.x*EPB;
  const ushort* src = yin + (size_t)e0*20*CIN;
  for(int i=tid; i<EPB*20*(CIN/8); i+=256){
    int c8 = i%(CIN/8); int rl = i/(CIN/8);
    int c = c8*8;
    short8 v = *(const short8*)(src + (size_t)rl*CIN + c);
    uint pk[4];
    #pragma unroll
    for(int jj=0;jj<4;jj++){
      float f0 = bf2f((ushort)v[jj*2]);
      float f1 = bf2f((ushort)v[jj*2+1]);
      f0=(f0-mi[c+jj*2  ][0])*mi[c+jj*2  ][1]; f0= f0>=0?f0:0.01f*f0;
      f1=(f1-mi[c+jj*2+1][0])*mi[c+jj*2+1][1]; f1= f1>=0?f1:0.01f*f1;
      pk[jj] = (uint)f2bf(f0) | ((uint)f2bf(f1)<<16);
    }
    int e = rl/20, l=rl%20;
    int row = e*22 + l + 1;
    uint byteoff = (uint)row*RB + (((uint)c*2) ^ (uint)((row&SWZ)<<4));
    *(uint4*)((char*)xs + byteoff) = make_uint4(pk[0],pk[1],pk[2],pk[3]);
  }
  __syncthreads();

  int lane = tid&63, wid = tid>>6;
  int l16 = lane&15, lhi = lane>>4;
  int colbase = wid*(OUT/4);
  f32x4 acc[ROWT][WCOLT];
  #pragma unroll
  for(int m=0;m<ROWT;m++)
    #pragma unroll
    for(int n=0;n<WCOLT;n++) acc[m][n]=(f32x4){0,0,0,0};
  int rowc[ROWT];
  #pragma unroll
  for(int m=0;m<ROWT;m++){ int r=m*16+l16; rowc[m]=(r/20)*22 + (r%20); }
  const ushort* wptile[WCOLT];
  #pragma unroll
  for(int n=0;n<WCOLT;n++)
    wptile[n] = wt + ((size_t)(wid*WCOLT + n)*KSTEPS)*512 + (size_t)lane*8;

  short8 aF0[ROWT], bF0[WCOLT], aF1[ROWT], bF1[WCOLT];

#define LOADK(ksv, A, B) { \
    int t_=(ksv)/(CIN/32); int c0_=((ksv)%(CIN/32))*32 + lhi*8; \
    _Pragma("unroll") \
    for(int m=0;m<ROWT;m++){ \
      int row_=rowc[m]+t_; \
      uint off_=(uint)row_*RB + (((uint)c0_*2) ^ (uint)((row_&SWZ)<<4)); \
      A[m]=*(const short8*)((char*)xs+off_); } \
    _Pragma("unroll") \
    for(int n=0;n<WCOLT;n++) B[n]=*(const short8*)(wptile[n]+(ksv)*512); }

#define MFMAK(A, B) { \
    _Pragma("unroll") \
    for(int m=0;m<ROWT;m++) \
      _Pragma("unroll") \
      for(int n=0;n<WCOLT;n++) \
        acc[m][n]=__builtin_amdgcn_mfma_f32_16x16x32_bf16(A[m],B[n],acc[m][n],0,0,0); }

  LOADK(0, aF0, bF0);
  #pragma unroll
  for(int kp=0; kp<KSTEPS/2; kp++){
    int ks = kp*2;
    LOADK(ks+1, aF1, bF1);
    MFMAK(aF0, bF0);
    if(ks+2<KSTEPS) LOADK(ks+2, aF0, bF0);
    MFMAK(aF1, bF1);
  }
#undef LOADK
#undef MFMAK

  #pragma unroll
  for(int n=0;n<WCOLT;n++){
    float s=0,q=0;
    #pragma unroll
    for(int m=0;m<ROWT;m++)
      #pragma unroll
      for(int j=0;j<4;j++){ float a=acc[m][n][j]; s+=a; q+=a*a; }
    s += __shfl_xor(s,16); s += __shfl_xor(s,32);
    q += __shfl_xor(q,16); q += __shfl_xor(q,32);
    if(lhi==0){
      int o = colbase+n*16+l16;
      atomicAdd(&ws[soOut+o], s);
      atomicAdd(&ws[soOutQ+o], q);
    }
  }
  ushort* dst = yout + (size_t)blockIdx.x*M*OUT;
  #pragma unroll
  for(int m=0;m<ROWT;m++)
    #pragma unroll
    for(int j=0;j<4;j++){
      int R = m*16 + lhi*4 + j;
      #pragma unroll
      for(int n=0;n<WCOLT;n++)
        dst[(size_t)R*OUT + colbase + n*16 + l16] = f2bf(acc[m][n][j]);
    }
}

// -------- fused pool+fc: mean_l lrelu(bn(y3 bf16)) -> fc -> fcb [E,16] + stats --------
__global__ __launch_bounds__(256) void k_poolfc(const float* __restrict__ fcw, float* __restrict__ ws){
  __shared__ float ps[16][260];
  __shared__ float red[4][32];
  __shared__ float mo[256][2];
  int tid=threadIdx.x;
  {
    float m=ws[SO_C3+tid]*(1.0f/81920.0f);
    float v=ws[SO_C3Q+tid]*(1.0f/81920.0f)-m*m; if(v<0)v=0;
    mo[tid][0]=m; mo[tid][1]=rsqrtf(v+EPSB);
  }
  __syncthreads();
  int e0=blockIdx.x*16;
  const ushort* y3=(const ushort*)(ws+F_Y13);
  float m=mo[tid][0], inv=mo[tid][1];
  for(int el=0;el<16;el++){
    const ushort* row=y3+((size_t)(e0+el)*20)*256+tid;
    float s=0;
    #pragma unroll
    for(int l=0;l<20;l++){
      float x=(bf2f(row[(size_t)l*256])-m)*inv;
      s += x>=0.f? x : 0.01f*x;
    }
    ps[el][tid]=s*(1.0f/20.0f);
  }
  __syncthreads();
  int e=tid>>4, h=tid&15;
  const float* wr=fcw+(size_t)h*256;
  float z=0;
  for(int c=0;c<256;c++) z+=ps[e][c]*wr[c];
  ws[F_FCB+(size_t)(e0+e)*16+h]=z;
  float s=z, q=z*z;
  #pragma unroll
  for(int o=16;o<64;o<<=1){ s+=__shfl_down(s,o); q+=__shfl_down(q,o); }
  int lane=tid&63, wid=tid>>6;
  if(lane<16){ red[wid][lane]=s; red[wid][16+lane]=q; }
  __syncthreads();
  if(tid<32){
    float v=red[0][tid]+red[1][tid]+red[2][tid]+red[3][tid];
    atomicAdd(&ws[tid<16? SO_FC+tid : SO_FCQ+(tid-16)], v);
  }
}

// -------- small-MLP layer-1 stats: grid 48 = 3 MLPs x 16 blocks --------
template<int DIM>
__device__ __forceinline__ void sm_l1_block(const float* __restrict__ x,
    const float* __restrict__ W1, float* __restrict__ ws, int so, int soq, int bid){
  __shared__ float w1s[16*DIM];
  int tid=threadIdx.x;
  if(tid<16*DIM) w1s[tid]=W1[tid];
  __syncthreads();
  int e=bid*256+tid;
  float xv[DIM];
  #pragma unroll
  for(int j=0;j<DIM;j++) xv[j]=x[(size_t)e*DIM+j];
  float s[16], q[16];
  #pragma unroll
  for(int k=0;k<16;k++){
    float z=0;
    #pragma unroll
    for(int j=0;j<DIM;j++) z+=w1s[k*DIM+j]*xv[j];
    s[k]=z; q[k]=z*z;
  }
  red32_atomic(ws, so, soq, s, q);
}

__global__ __launch_bounds__(256) void k_sm_l1(
    const float* __restrict__ et, const float* __restrict__ el, const float* __restrict__ ev,
    const float* __restrict__ etW1, const float* __restrict__ elW1, const float* __restrict__ evW1,
    float* __restrict__ ws){
  int g=blockIdx.x>>4, bid=blockIdx.x&15;
  if(g==0)      sm_l1_block<11>(et,etW1,ws,SO_ET1,SO_ET1Q,bid);
  else if(g==1) sm_l1_block<1> (el,elW1,ws,SO_EL1,SO_EL1Q,bid);
  else          sm_l1_block<3> (ev,evW1,ws,SO_EV1,SO_EV1Q,bid);
}

// -------- small-MLP layer-2: z2 raw + stats: grid 48 --------
template<int DIM>
__device__ __forceinline__ void sm_l2_block(const float* __restrict__ x,
    const float* __restrict__ W1, const float* __restrict__ W2,
    float* __restrict__ ws, int so1, int so1q, int so2, int so2q,
    float* __restrict__ z2out, int bid){
  __shared__ float w1s[16*DIM];
  __shared__ float w2s[256];
  __shared__ float mi[16][2];
  int tid=threadIdx.x;
  if(tid<16*DIM) w1s[tid]=W1[tid];
  w2s[tid]=W2[tid];
  if(tid<16){
    float m=ws[so1+tid]*(1.0f/4096.0f);
    float v=ws[so1q+tid]*(1.0f/4096.0f)-m*m; if(v<0)v=0;
    mi[tid][0]=m; mi[tid][1]=rsqrtf(v+EPSB);
  }
  __syncthreads();
  int e=bid*256+tid;
  float xv[DIM];
  #pragma unroll
  for(int j=0;j<DIM;j++) xv[j]=x[(size_t)e*DIM+j];
  float h1[16];
  #pragma unroll
  for(int h=0;h<16;h++){
    float z=0;
    #pragma unroll
    for(int j=0;j<DIM;j++) z+=w1s[h*DIM+j]*xv[j];
    z=(z-mi[h][0])*mi[h][1];
    h1[h]=z>0?z:0;
  }
  float s[16], q[16];
  #pragma unroll
  for(int k=0;k<16;k++){
    float z=0;
    #pragma unroll
    for(int h=0;h<16;h++) z+=w2s[k*16+h]*h1[h];
    z2out[(size_t)e*16+k]=z;
    s[k]=z; q[k]=z*z;
  }
  red32_atomic(ws, so2, so2q, s, q);
}

__global__ __launch_bounds__(256) void k_sm_l2(
    const float* __restrict__ et, const float* __restrict__ el, const float* __restrict__ ev,
    const float* __restrict__ etW1, const float* __restrict__ etW2,
    const float* __restrict__ elW1, const float* __restrict__ elW2,
    const float* __restrict__ evW1, const float* __restrict__ evW2,
    float* __restrict__ ws){
  int g=blockIdx.x>>4, bid=blockIdx.x&15;
  if(g==0)      sm_l2_block<11>(et,etW1,etW2,ws,SO_ET1,SO_ET1Q,SO_ET2,SO_ET2Q,ws+F_Z2T,bid);
  else if(g==1) sm_l2_block<1> (el,elW1,elW2,ws,SO_EL1,SO_EL1Q,SO_EL2,SO_EL2Q,ws+F_Z2T+65536,bid);
  else          sm_l2_block<3> (ev,evW1,evW2,ws,SO_EV1,SO_EV1Q,SO_EV2,SO_EV2Q,ws+F_Z2T+131072,bid);
}

// ---------------- ef assembly: BN-apply stored z2s + fc-bn -> ef [E,16] ----------------
__device__ __constant__ int EF_BASES[4][2] = {
  {SO_ET2,SO_ET2Q},{SO_EL2,SO_EL2Q},{SO_EV2,SO_EV2Q},{SO_FC,SO_FCQ}
};

__global__ __launch_bounds__(256) void k_ef(float* __restrict__ ws){
  __shared__ float mi[4][16][2];
  int tid=threadIdx.x;
  if(tid<64){
    int g=tid>>4, h=tid&15;
    float m=ws[EF_BASES[g][0]+h]*(1.0f/4096.0f);
    float v=ws[EF_BASES[g][1]+h]*(1.0f/4096.0f)-m*m; if(v<0)v=0;
    mi[g][h][0]=m; mi[g][h][1]=rsqrtf(v+EPSB);
  }
  __syncthreads();
  int e=blockIdx.x*256+tid;
  float acc[16];
  #pragma unroll
  for(int h=0;h<16;h++){
    float z=ws[F_FCB+(size_t)e*16+h];
    acc[h]=(z-mi[3][h][0])*mi[3][h][1];   // fc: BN, no relu
  }
  #pragma unroll
  for(int g=0;g<3;g++){
    const float* z2=ws+F_Z2T+(size_t)g*65536;
    #pragma unroll
    for(int k=0;k<16;k++){
      float z=z2[(size_t)e*16+k];
      float r=(z-mi[g][k][0])*mi[g][k][1];
      acc[k]+= r>0?r:0;
    }
  }
  #pragma unroll
  for(int h=0;h<16;h++) ws[F_EF+(size_t)e*16+h]=acc[h];
}

// ---------------- proj: node_feat @ ec_Wp.T -> proj [1024,16] ----------------
__global__ __launch_bounds__(256) void k_proj(const float* __restrict__ nf,
    const float* __restrict__ Wp, float* __restrict__ ws){
  __shared__ float wps[4096];
  int tid=threadIdx.x;
  for(int i=tid;i<4096;i+=256) wps[i]=Wp[i];
  __syncthreads();
  int t=blockIdx.x*256+tid;
  int v=t>>4, h=t&15;
  const float* row=nf+(size_t)v*256;
  const float* wr=wps+h*256;
  float z=0;
  for(int c=0;c<256;c++) z+=row[c]*wr[c];
  ws[F_PROJ+t]=z;
}

// ---------------- agg + edgeconv layer1 -> z1ec [E,64] + stats ----------------
__global__ __launch_bounds__(256) void k_agg(const int* __restrict__ src, const int* __restrict__ dst,
    const float* __restrict__ ecW1, float* __restrict__ ws){
  __shared__ float w1s[1024];
  int tid=threadIdx.x;
  for(int i=tid;i<1024;i+=256) w1s[i]=ecW1[i];
  __syncthreads();
  int e=blockIdx.x*256+tid;
  int s=src[e], d=dst[e];
  float a[16];
  #pragma unroll
  for(int h=0;h<16;h++)
    a[h]=ws[F_EF+(size_t)e*16+h]+ws[F_PROJ+(size_t)s*16+h]+ws[F_PROJ+(size_t)d*16+h];
  int lane=tid&63;
  for(int o=0;o<64;o++){
    float z=0;
    #pragma unroll
    for(int h=0;h<16;h++) z+=w1s[o*16+h]*a[h];
    ws[F_Z1EC+(size_t)e*64+o]=z;
    float rs=waveSum(z), rq=waveSum(z*z);
    if(lane==0){ atomicAdd(&ws[SO_G1+o],rs); atomicAdd(&ws[SO_G1Q+o],rq); }
  }
}

// ---------------- edgeconv layer2 -> z2 [E,16] (in F_FCB) + stats ----------------
__global__ __launch_bounds__(256) void k_ec2(const float* __restrict__ ecW2, float* __restrict__ ws){
  __shared__ float w2s[1024];
  __shared__ float mi[64][2];
  __shared__ float red[4][32];
  int tid=threadIdx.x;
  for(int i=tid;i<1024;i+=256) w2s[i]=ecW2[i];
  if(tid<64){
    float m=ws[SO_G1+tid]*(1.0f/4096.0f);
    float v=ws[SO_G1Q+tid]*(1.0f/4096.0f)-m*m; if(v<0)v=0;
    mi[tid][0]=m; mi[tid][1]=rsqrtf(v+EPSB);
  }
  __syncthreads();
  int e=blockIdx.x*256+tid;
  float acc[16];
  #pragma unroll
  for(int k=0;k<16;k++) acc[k]=0;
  for(int o=0;o<64;o++){
    float z=ws[F_Z1EC+(size_t)e*64+o];
    float h=(z-mi[o][0])*mi[o][1];
    h=h>0?h:0;
    #pragma unroll
    for(int k=0;k<16;k++) acc[k]+=w2s[k*64+o]*h;
  }
  float s[16], q[16];
  #pragma unroll
  for(int k=0;k<16;k++){
    ws[F_FCB+(size_t)e*16+k]=acc[k];
    s[k]=acc[k]; q[k]=acc[k]*acc[k];
  }
  int lane=tid&63, wid=tid>>6;
  #pragma unroll
  for(int k=0;k<16;k++){
    float rs=waveSum(s[k]), rq=waveSum(q[k]);
    if(lane==0){ red[wid][k]=rs; red[wid][16+k]=rq; }
  }
  __syncthreads();
  if(tid<32){
    float t=red[0][tid]+red[1][tid]+red[2][tid]+red[3][tid];
    atomicAdd(&ws[tid<16 ? SO_G2+tid : SO_G2Q+(tid-16)], t);
  }
}

// ---------------- edge_feature fill [4,1025,16] ----------------
__global__ __launch_bounds__(256) void k_ef2(float* __restrict__ ws){
  int t=blockIdx.x*256+threadIdx.x;
  if(t>=4*1025*16) return;
  int h=t&15, r=t>>4;
  int b=r/1025, pos=r%1025;
  float v=0;
  if(pos<1024){
    int e=b*1024+pos;
    float z=ws[F_FCB+(size_t)e*16+h];
    float m=ws[SO_G2+h]*(1.0f/4096.0f);
    float va=ws[SO_G2Q+h]*(1.0f/4096.0f)-m*m; if(va<0)va=0;
    v=(z-m)*rsqrtf(va+EPSB);
    v=v>0?v:0;
  }
  ws[F_EDGEF+t]=v;
}

// ---------------- main per-pair kernel: interior output ----------------
__global__ __launch_bounds__(256) void k_pair(const float* __restrict__ ab,
    const int* __restrict__ sd, const float* __restrict__ ang, const float* __restrict__ cen,
    const int* __restrict__ ep, const float* __restrict__ sdemb, const float* __restrict__ edisw,
    const float* __restrict__ angW1, const float* __restrict__ angW2,
    const float* __restrict__ cenW1, const float* __restrict__ cenW2,
    const float* __restrict__ ws, float* __restrict__ out){
  __shared__ float wd[1280];
  __shared__ float w2a[256], w2c[256];
  __shared__ float Aa[16], Ac[16], m2a[16], i2a[16], m2c[16], i2c[16];
  __shared__ float muA, muC, varA, varC;
  int tid=threadIdx.x;
  for(int i=tid;i<1280;i+=256) wd[i]=edisw[i];
  w2a[tid]=angW2[tid]; w2c[tid]=cenW2[tid];
  if(tid==0){
    float s=ws[SO_ANGX], q=ws[SO_ANGX+1];
    float mu=s*(1.0f/262144.0f);
    float v=q*(1.0f/262144.0f)-mu*mu; if(v<0)v=0;
    muA=mu; varA=v;
    s=ws[SO_CENX]; q=ws[SO_CENX+1];
    mu=s*(1.0f/262144.0f);
    v=q*(1.0f/262144.0f)-mu*mu; if(v<0)v=0;
    muC=mu; varC=v;
  }
  __syncthreads();
  if(tid<16){
    float w=angW1[tid]; Aa[tid]=w/sqrtf(varA*w*w+EPSB);
    float m=ws[SO_ANG2+tid]*(1.0f/262144.0f);
    float v=ws[SO_ANG2Q+tid]*(1.0f/262144.0f)-m*m; if(v<0)v=0;
    m2a[tid]=m; i2a[tid]=rsqrtf(v+EPSB);
  } else if(tid<32){
    int h=tid-16;
    float w=cenW1[h]; Ac[h]=w/sqrtf(varC*w*w+EPSB);
    float m=ws[SO_CEN2+h]*(1.0f/262144.0f);
    float v=ws[SO_CEN2Q+h]*(1.0f/262144.0f)-m*m; if(v<0)v=0;
    m2c[h]=m; i2c[h]=rsqrtf(v+EPSB);
  }
  __syncthreads();
  int t=blockIdx.x*256+tid;            // b,i,j
  int b=t>>16, rem=t&65535, i=rem>>8, j=rem&255;
  int sdv=sd[t];
  float xa=ang[t], xc0=cen[t];
  float acc[16];
  const float* se=sdemb+(size_t)sdv*16;
  #pragma unroll
  for(int k=0;k<16;k++) acc[k]=se[k];
  { // angle MLP
    float xc=xa-muA;
    float h1[16];
    #pragma unroll
    for(int h=0;h<16;h++){ float v=xc*Aa[h]; h1[h]=v>0?v:0; }
    #pragma unroll
    for(int k=0;k<16;k++){
      float z=0;
      #pragma unroll
      for(int h=0;h<16;h++) z+=w2a[k*16+h]*h1[h];
      float r=(z-m2a[k])*i2a[k];
      acc[k]+= r>0?r:0;
    }
  }
  { // centroid MLP
    float xc=xc0-muC;
    float h1[16];
    #pragma unroll
    for(int h=0;h<16;h++){ float v=xc*Ac[h]; h1[h]=v>0?v:0; }
    #pragma unroll
    for(int k=0;k<16;k++){
      float z=0;
      #pragma unroll
      for(int h=0;h<16;h++) z+=w2c[k*16+h]*h1[h];
      float r=(z-m2c[k])*i2c[k];
      acc[k]+= r>0?r:0;
    }
  }
  { // multi-hop edge bias
    int sdm = sdv==0 ? 1 : sdv;
    if(sdm>1) sdm-=1;
    if(sdm>5) sdm=5;
    float inv=1.0f/((float)sdm+1e-6f);
    float eb[16];
    #pragma unroll
    for(int k=0;k<16;k++) eb[k]=0;
    const float* EF=ws+F_EDGEF+(size_t)b*1025*16;
    #pragma unroll
    for(int d=0;d<5;d++){
      int idx=ep[(size_t)t*5+d];
      const float* r=EF+(size_t)idx*16;
      float e16[16];
      #pragma unroll
      for(int k=0;k<16;k+=4){
        float4 v=*(const float4*)(r+k);
        e16[k]=v.x; e16[k+1]=v.y; e16[k+2]=v.z; e16[k+3]=v.w;
      }
      const float* wdd=wd+d*256;
      #pragma unroll
      for(int h=0;h<16;h++){
        float evv=e16[h];
        const float4* wv4=(const float4*)(wdd+h*16);
        #pragma unroll
        for(int k4=0;k4<4;k4++){
          float4 wv=wv4[k4];
          eb[k4*4+0]+=evv*wv.x; eb[k4*4+1]+=evv*wv.y;
          eb[k4*4+2]+=evv*wv.z; eb[k4*4+3]+=evv*wv.w;
        }
      }
    }
    #pragma unroll
    for(int k=0;k<16;k++) acc[k]+=eb[k]*inv;
  }
  float base2=2.0f*ab[(size_t)b*66049+(size_t)(i+1)*257+(j+1)];
  #pragma unroll
  for(int k=0;k<16;k++)
    out[(((size_t)b*16+k)*257+(i+1))*257+(j+1)]=acc[k]+base2;
}

// ---------------- borders: row 0 and col 0 ----------------
__global__ __launch_bounds__(256) void k_border(const float* __restrict__ ab,
    const float* __restrict__ virt, float* __restrict__ out){
  int t=blockIdx.x*256+threadIdx.x;
  if(t>=4*16*513) return;
  int idx=t%513, bh=t/513;
  int b=bh>>4, h=bh&15;
  float v=virt[h];
  if(idx<257){
    out[(((size_t)b*16+h)*257)*257+idx]=2.0f*ab[(size_t)b*66049+idx]+v;
  } else {
    int p=idx-256;   // 1..256
    out[(((size_t)b*16+h)*257+p)*257]=2.0f*ab[(size_t)b*66049+(size_t)p*257]+v;
  }
}

extern "C" void kernel_launch(void* const* d_in, const int* in_sizes, int n_in,
                              void* d_out, int out_size, void* d_ws, size_t ws_size,
                              hipStream_t stream) {
  const float* ab    =(const float*)d_in[0];
  const int*   sdist =(const int*)  d_in[1];
  const float* ang   =(const float*)d_in[2];
  const float* cen   =(const float*)d_in[3];
  const int*   ep    =(const int*)  d_in[4];
  const float* edata =(const float*)d_in[5];
  const float* etype =(const float*)d_in[6];
  const float* elen  =(const float*)d_in[7];
  const float* econv =(const float*)d_in[8];
  const int*   src   =(const int*)  d_in[10];
  const int*   dst   =(const int*)  d_in[11];
  const float* nf    =(const float*)d_in[12];
  const float* sdemb =(const float*)d_in[13];
  const float* virt  =(const float*)d_in[14];
  const float* angW1 =(const float*)d_in[15];
  const float* angW2 =(const float*)d_in[16];
  const float* cenW1 =(const float*)d_in[17];
  const float* cenW2 =(const float*)d_in[18];
  const float* etW1  =(const float*)d_in[19];
  const float* etW2  =(const float*)d_in[20];
  const float* elW1  =(const float*)d_in[21];
  const float* elW2  =(const float*)d_in[22];
  const float* evW1  =(const float*)d_in[23];
  const float* evW2  =(const float*)d_in[24];
  const float* c1w   =(const float*)d_in[25];
  const float* c2w   =(const float*)d_in[26];
  const float* c3w   =(const float*)d_in[27];
  const float* fcw   =(const float*)d_in[28];
  const float* edisw =(const float*)d_in[29];
  const float* ecWp  =(const float*)d_in[30];
  const float* ecW1  =(const float*)d_in[31];
  const float* ecW2  =(const float*)d_in[32];
  float* ws=(float*)d_ws;
  float* out=(float*)d_out;

  hipMemsetAsync(d_ws, 0, STATS_FLOATS*sizeof(float), stream);

  k_wprep<<<480,256,0,stream>>>(c2w,c3w,(ushort*)(ws+F_WT2),(ushort*)(ws+F_WT3));

  k_scalar_stats<<<256,256,0,stream>>>(ang,cen,ws);
  k_acl2<<<256,256,0,stream>>>(ang,cen,angW1,angW2,cenW1,cenW2,ws);

  k_conv1<<<256,256,0,stream>>>(edata,c1w,ws);
  k_convmf<64,128,8><<<512,256,0,stream>>>((const ushort*)(ws+F_Y13),(const ushort*)(ws+F_WT2),
                                           (ushort*)(ws+F_Y2),ws,SO_C1,SO_C1Q,SO_C2,SO_C2Q);
  k_convmf<128,256,4><<<1024,256,0,stream>>>((const ushort*)(ws+F_Y2),(const ushort*)(ws+F_WT3),
                                             (ushort*)(ws+F_Y13),ws,SO_C2,SO_C2Q,SO_C3,SO_C3Q);
  k_poolfc<<<256,256,0,stream>>>(fcw,ws);

  k_sm_l1<<<48,256,0,stream>>>(etype,elen,econv,etW1,elW1,evW1,ws);
  k_sm_l2<<<48,256,0,stream>>>(etype,elen,econv,etW1,etW2,elW1,elW2,evW1,evW2,ws);

  k_ef<<<16,256,0,stream>>>(ws);
  k_proj<<<64,256,0,stream>>>(nf,ecWp,ws);
  k_agg<<<16,256,0,stream>>>(src,dst,ecW1,ws);
  k_ec2<<<16,256,0,stream>>>(ecW2,ws);
  k_ef2<<<257,256,0,stream>>>(ws);

  k_pair<<<1024,256,0,stream>>>(ab,sdist,ang,cen,ep,sdemb,edisw,angW1,angW2,cenW1,cenW2,ws,out);
  k_border<<<129,256,0,stream>>>(ab,virt,out);
}

// Round 7
// 255.849 us; speedup vs baseline: 1.5794x; 1.1225x over previous
//
#include <hip/hip_runtime.h>

#define EPSB 1e-5f
#define B_ 4
#define N_ 256
#define H_ 16
#define D_ 5
#define E_ 4096
#define M_PAIR (B_*N_*N_)   // 262144

typedef __attribute__((ext_vector_type(8))) short short8;
typedef __attribute__((ext_vector_type(4))) float f32x4;

// ---- stats slot offsets (floats) in ws ----
enum {
  SO_ANGX = 0,   // ang sum, ang sq
  SO_CENX = 2,   // cen sum, cen sq
  SO_MOMA = 16,  // P, N, Pq, Nq for angle dx
  SO_MOMC = 24,  // same for centroid
  SO_C1   = 96,  SO_C1Q   = 160,
  SO_C2   = 224, SO_C2Q   = 352,
  SO_C3   = 480, SO_C3Q   = 736,
  SO_FC   = 992, SO_FCQ   = 1008,
  SO_ET1  = 1024, SO_ET1Q = 1040,
  SO_ET2  = 1056, SO_ET2Q = 1072,
  SO_EL1  = 1088, SO_EL1Q = 1104,
  SO_EL2  = 1120, SO_EL2Q = 1136,
  SO_EV1  = 1152, SO_EV1Q = 1168,
  SO_EV2  = 1184, SO_EV2Q = 1200,
  SO_G1   = 1216, SO_G1Q  = 1280,
  SO_G2   = 1344, SO_G2Q  = 1360,
  STATS_FLOATS = 2048
};

// ---- buffer offsets (floats) ----
static constexpr size_t F_Y13  = 2048;                 // y1 bf16 [E][20][64] / y3 bf16 [E][20][256]
static constexpr size_t F_Y2   = F_Y13 + 10485760;     // y2 bf16 [E][20][128]
static constexpr size_t F_POOL = F_Y2 + 5242880;       // slack
static constexpr size_t F_FCB  = F_POOL + 1048576;     // E*16 (fc out, later z2 of edgeconv)
static constexpr size_t F_EF   = F_FCB + 65536;        // slack
static constexpr size_t F_PROJ = F_EF + 65536;         // 1024*16
static constexpr size_t F_Z1EC = F_PROJ + 16384;       // E*64
static constexpr size_t F_Z2T  = F_Z1EC + 262144;      // 3 x E*16 raw z2
static constexpr size_t F_G    = F_Z2T + 196608;       // [4][1025][5][16] = 328000
static constexpr size_t F_WT2  = F_G + 328000;         // 128*192 bf16
static constexpr size_t F_WT3  = F_WT2 + 12288;        // 256*384 bf16

__device__ __forceinline__ float waveSum(float v){
  #pragma unroll
  for(int o=32;o;o>>=1) v += __shfl_down(v,o);
  return v;
}

__device__ __forceinline__ ushort f2bf(float f){
  uint u = __float_as_uint(f);
  uint r = (u + 0x7FFF + ((u>>16)&1)) >> 16;
  return (ushort)r;
}
__device__ __forceinline__ float bf2f(ushort u){
  return __uint_as_float(((uint)u)<<16);
}

// block = 256 threads. Reduce 16 sums + 16 sumsqs, atomicAdd to ws.
__device__ __forceinline__ void red32_atomic(float* ws, int so, int soq, float* s, float* q){
  __shared__ float red[4][32];
  int tid=threadIdx.x, lane=tid&63, wid=tid>>6;
  #pragma unroll
  for(int k=0;k<16;k++){
    float rs=waveSum(s[k]), rq=waveSum(q[k]);
    if(lane==0){ red[wid][k]=rs; red[wid][16+k]=rq; }
  }
  __syncthreads();
  if(tid<32){
    float t=red[0][tid]+red[1][tid]+red[2][tid]+red[3][tid];
    atomicAdd(&ws[tid<16 ? so+tid : soq+(tid-16)], t);
  }
}

// ================= k_front device pieces (all mutually independent) =================

__device__ void dev_conv1(int bid, const float* __restrict__ ed,
    const float* __restrict__ w, float* __restrict__ ws){
  __shared__ float wsh[64*36];
  __shared__ float xs[16][12][20];
  __shared__ float reds[4][64], redq[4][64];
  int tid=threadIdx.x;
  for(int i=tid;i<64*36;i+=256) wsh[i]=w[i];
  int e0=bid*16;
  for(int i=tid;i<16*240;i+=256){
    int e=i/240, r=i%240, l=r/12, c=r%12;
    xs[e][c][l]=ed[(size_t)(e0+e)*240+r];
  }
  __syncthreads();
  int o=tid&63, eg=tid>>6;
  ushort* y1=(ushort*)(ws+F_Y13);
  float ssum=0, ssq=0;
  for(int ee=0;ee<4;ee++){
    int e=eg*4+ee;
    float acc[20];
    #pragma unroll
    for(int l=0;l<20;l++) acc[l]=0;
    for(int c=0;c<12;c++){
      float w0=wsh[o*36+c*3], w1=wsh[o*36+c*3+1], w2=wsh[o*36+c*3+2];
      const float* xr=xs[e][c];
      #pragma unroll
      for(int l=0;l<20;l++){
        acc[l]=fmaf(w1,xr[l],acc[l]);
        if(l>0)  acc[l]=fmaf(w0,xr[l-1],acc[l]);
        if(l<19) acc[l]=fmaf(w2,xr[l+1],acc[l]);
      }
    }
    size_t base=((size_t)(e0+e)*20)*64;
    #pragma unroll
    for(int l=0;l<20;l++){
      y1[base+(size_t)l*64+o]=f2bf(acc[l]);
      ssum+=acc[l]; ssq+=acc[l]*acc[l];
    }
  }
  reds[eg][o]=ssum; redq[eg][o]=ssq;
  __syncthreads();
  if(tid<64){
    float s=reds[0][tid]+reds[1][tid]+reds[2][tid]+reds[3][tid];
    atomicAdd(&ws[SO_C1+tid], s);
  } else if(tid<128){
    int oo=tid-64;
    float q=redq[0][oo]+redq[1][oo]+redq[2][oo]+redq[3][oo];
    atomicAdd(&ws[SO_C1Q+oo], q);
  }
}

__device__ void dev_wprep(int bid, const float* __restrict__ c2w,
    const float* __restrict__ c3w, ushort* __restrict__ wt2, ushort* __restrict__ wt3){
  int t = bid*256 + threadIdx.x;
  if(t < 128*192){
    int idx=t;
    int j=idx&7, lane=(idx>>3)&63, ks=(idx>>9)%6, ct=idx/3072;
    int l16=lane&15, lhi=lane>>4;
    int o=ct*16+l16, tap=ks/2, c=(ks%2)*32+lhi*8+j;
    wt2[idx]=f2bf(c2w[(o*64+c)*3+tap]);
  } else {
    int idx=t-128*192;
    if(idx<256*384){
      int j=idx&7, lane=(idx>>3)&63, ks=(idx>>9)%12, ct=idx/6144;
      int l16=lane&15, lhi=lane>>4;
      int o=ct*16+l16, tap=ks/4, c=(ks%4)*32+lhi*8+j;
      wt3[idx]=f2bf(c3w[(o*128+c)*3+tap]);
    }
  }
}

__device__ void dev_proj(int bid, const float* __restrict__ nf,
    const float* __restrict__ Wp, float* __restrict__ ws){
  __shared__ float wps[4096];
  int tid=threadIdx.x;
  for(int i=tid;i<4096;i+=256) wps[i]=Wp[i];
  __syncthreads();
  int t=bid*256+tid;
  int v=t>>4, h=t&15;
  const float* row=nf+(size_t)v*256;
  const float* wr=wps+h*256;
  float z=0;
  for(int c=0;c<256;c++) z+=row[c]*wr[c];
  ws[F_PROJ+t]=z;
}

__device__ void dev_scalar(int bid, const float* __restrict__ ang,
    const float* __restrict__ cen, float* __restrict__ st){
  int tid = bid*256 + threadIdx.x;
  float sa=0, qa=0, sc=0, qc=0;
  for(int i=tid; i<M_PAIR; i += 256*256){
    float a=ang[i], c=cen[i];
    sa+=a; qa+=a*a; sc+=c; qc+=c*c;
  }
  __shared__ float red[4][4];
  int lane=threadIdx.x&63, wid=threadIdx.x>>6;
  sa=waveSum(sa); qa=waveSum(qa); sc=waveSum(sc); qc=waveSum(qc);
  if(lane==0){ red[wid][0]=sa; red[wid][1]=qa; red[wid][2]=sc; red[wid][3]=qc; }
  __syncthreads();
  if(threadIdx.x<4){
    float t=red[0][threadIdx.x]+red[1][threadIdx.x]+red[2][threadIdx.x]+red[3][threadIdx.x];
    atomicAdd(&st[threadIdx.x], t);
  }
}

template<int DIM>
__device__ void dev_sml1(const float* __restrict__ x,
    const float* __restrict__ W1, float* __restrict__ ws, int so, int soq, int bid){
  __shared__ float w1s[176];
  int tid=threadIdx.x;
  if(tid<16*DIM) w1s[tid]=W1[tid];
  __syncthreads();
  int e=bid*256+tid;
  float xv[DIM];
  #pragma unroll
  for(int j=0;j<DIM;j++) xv[j]=x[(size_t)e*DIM+j];
  float s[16], q[16];
  #pragma unroll
  for(int k=0;k<16;k++){
    float z=0;
    #pragma unroll
    for(int j=0;j<DIM;j++) z+=w1s[k*DIM+j]*xv[j];
    s[k]=z; q[k]=z*z;
  }
  red32_atomic(ws, so, soq, s, q);
}

// blocks: [0,256) conv1 | [256,736) wprep | [736,800) proj | [800,1056) scalar | [1056,1104) sml1
__global__ __launch_bounds__(256) void k_front(
    const float* __restrict__ ed, const float* __restrict__ c1w,
    const float* __restrict__ c2w, const float* __restrict__ c3w,
    const float* __restrict__ nf, const float* __restrict__ Wp,
    const float* __restrict__ ang, const float* __restrict__ cen,
    const float* __restrict__ et, const float* __restrict__ el, const float* __restrict__ ev,
    const float* __restrict__ etW1, const float* __restrict__ elW1, const float* __restrict__ evW1,
    float* __restrict__ ws){
  int bx=blockIdx.x;
  if(bx<256)       dev_conv1(bx, ed, c1w, ws);
  else if(bx<736)  dev_wprep(bx-256, c2w, c3w, (ushort*)(ws+F_WT2), (ushort*)(ws+F_WT3));
  else if(bx<800)  dev_proj(bx-736, nf, Wp, ws);
  else if(bx<1056) dev_scalar(bx-800, ang, cen, ws);
  else {
    int bid=bx-1056;
    int g=bid>>4, b2=bid&15;
    if(g==0)      dev_sml1<11>(et,etW1,ws,SO_ET1,SO_ET1Q,b2);
    else if(g==1) dev_sml1<1> (el,elW1,ws,SO_EL1,SO_EL1Q,b2);
    else          dev_sml1<3> (ev,evW1,ws,SO_EV1,SO_EV1Q,b2);
  }
}

// ================= k_stats2: moments (needs mu) + small-MLP layer2 =================

__device__ void dev_mom2(int bid, const float* __restrict__ x, float* __restrict__ st,
    int soX, int mo){
  int tid=threadIdx.x;
  float mu = st[soX]*(1.0f/262144.0f);
  float P=0,N=0,Pq=0,Nq=0;
  for(int i=bid*256+tid; i<M_PAIR; i+=32*256){
    float dx=x[i]-mu;
    if(dx>0){ P+=dx; Pq+=dx*dx; } else { N+=dx; Nq+=dx*dx; }
  }
  __shared__ float red[4][4];
  int lane=tid&63, wid=tid>>6;
  P=waveSum(P); N=waveSum(N); Pq=waveSum(Pq); Nq=waveSum(Nq);
  if(lane==0){ red[wid][0]=P; red[wid][1]=N; red[wid][2]=Pq; red[wid][3]=Nq; }
  __syncthreads();
  if(tid<4){
    float t=red[0][tid]+red[1][tid]+red[2][tid]+red[3][tid];
    atomicAdd(&st[mo+tid], t);
  }
}

template<int DIM>
__device__ void dev_sml2(const float* __restrict__ x,
    const float* __restrict__ W1, const float* __restrict__ W2,
    float* __restrict__ ws, int so1, int so1q, int so2, int so2q,
    float* __restrict__ z2out, int bid){
  __shared__ float w1s[176];
  __shared__ float w2s[256];
  __shared__ float mi[16][2];
  int tid=threadIdx.x;
  if(tid<16*DIM) w1s[tid]=W1[tid];
  w2s[tid]=W2[tid];
  if(tid<16){
    float m=ws[so1+tid]*(1.0f/4096.0f);
    float v=ws[so1q+tid]*(1.0f/4096.0f)-m*m; if(v<0)v=0;
    mi[tid][0]=m; mi[tid][1]=rsqrtf(v+EPSB);
  }
  __syncthreads();
  int e=bid*256+tid;
  float xv[DIM];
  #pragma unroll
  for(int j=0;j<DIM;j++) xv[j]=x[(size_t)e*DIM+j];
  float h1[16];
  #pragma unroll
  for(int h=0;h<16;h++){
    float z=0;
    #pragma unroll
    for(int j=0;j<DIM;j++) z+=w1s[h*DIM+j]*xv[j];
    z=(z-mi[h][0])*mi[h][1];
    h1[h]=z>0?z:0;
  }
  float s[16], q[16];
  #pragma unroll
  for(int k=0;k<16;k++){
    float z=0;
    #pragma unroll
    for(int h=0;h<16;h++) z+=w2s[k*16+h]*h1[h];
    z2out[(size_t)e*16+k]=z;
    s[k]=z; q[k]=z*z;
  }
  red32_atomic(ws, so2, so2q, s, q);
}

// blocks: [0,32) mom ang | [32,64) mom cen | [64,112) sml2
__global__ __launch_bounds__(256) void k_stats2(
    const float* __restrict__ ang, const float* __restrict__ cen,
    const float* __restrict__ et, const float* __restrict__ el, const float* __restrict__ ev,
    const float* __restrict__ etW1, const float* __restrict__ etW2,
    const float* __restrict__ elW1, const float* __restrict__ elW2,
    const float* __restrict__ evW1, const float* __restrict__ evW2,
    float* __restrict__ ws){
  int bx=blockIdx.x;
  if(bx<32)       dev_mom2(bx, ang, ws, SO_ANGX, SO_MOMA);
  else if(bx<64)  dev_mom2(bx-32, cen, ws, SO_CENX, SO_MOMC);
  else {
    int bid=bx-64;
    int g=bid>>4, b2=bid&15;
    if(g==0)      dev_sml2<11>(et,etW1,etW2,ws,SO_ET1,SO_ET1Q,SO_ET2,SO_ET2Q,ws+F_Z2T,b2);
    else if(g==1) dev_sml2<1> (el,elW1,elW2,ws,SO_EL1,SO_EL1Q,SO_EL2,SO_EL2Q,ws+F_Z2T+65536,b2);
    else          dev_sml2<3> (ev,evW1,evW2,ws,SO_EV1,SO_EV1Q,SO_EV2,SO_EV2Q,ws+F_Z2T+131072,b2);
  }
}

// ---------------- MFMA conv (conv2/conv3) ----------------
template<int CIN, int OUT, int EPB, int NSPLIT>
__global__ __launch_bounds__(256) void k_convmf(
    const ushort* __restrict__ yin, const ushort* __restrict__ wt,
    ushort* __restrict__ yout, float* __restrict__ ws,
    int soIn, int soInQ, int soOut, int soOutQ)
{
  constexpr int K = CIN*3;
  constexpr int KSTEPS = K/32;
  constexpr int M = EPB*20;
  constexpr int ROWT = M/16;
  constexpr int WCOLT = OUT/(64*NSPLIT);
  constexpr int ROWS = EPB*22;
  constexpr int RB = CIN*2;
  constexpr uint SWZ = RB/16 - 1;
  __shared__ ushort xs[ROWS*CIN];
  __shared__ float mi[CIN][2];
  int tid = threadIdx.x;
  int bx = blockIdx.x;
  int eblk = bx / NSPLIT, split = bx % NSPLIT;
  for(int c=tid; c<CIN; c+=256){
    float m=ws[soIn+c]*(1.0f/81920.0f);
    float v=ws[soInQ+c]*(1.0f/81920.0f)-m*m; if(v<0)v=0;
    mi[c][0]=m; mi[c][1]=rsqrtf(v+EPSB);
  }
  uint* xs32 = (uint*)xs;
  for(int i=tid; i<EPB*2*(CIN/2); i+=256){
    int e=i/(CIN), r=i%(CIN); int lp = (r < CIN/2)? 0:21; int cw = r%(CIN/2);
    xs32[(e*22+lp)*(CIN/2)+cw]=0;
  }
  __syncthreads();
  int e0 = eblk*EPB;
  const ushort* src = yin + (size_t)e0*20*CIN;
  for(int i=tid; i<EPB*20*(CIN/8); i+=256){
    int c8 = i%(CIN/8); int rl = i/(CIN/8);
    int c = c8*8;
    short8 v = *(const short8*)(src + (size_t)rl*CIN + c);
    uint pk[4];
    #pragma unroll
    for(int jj=0;jj<4;jj++){
      float f0 = bf2f((ushort)v[jj*2]);
      float f1 = bf2f((ushort)v[jj*2+1]);
      f0=(f0-mi[c+jj*2  ][0])*mi[c+jj*2  ][1]; f0= f0>=0?f0:0.01f*f0;
      f1=(f1-mi[c+jj*2+1][0])*mi[c+jj*2+1][1]; f1= f1>=0?f1:0.01f*f1;
      pk[jj] = (uint)f2bf(f0) | ((uint)f2bf(f1)<<16);
    }
    int e = rl/20, l=rl%20;
    int row = e*22 + l + 1;
    uint byteoff = (uint)row*RB + (((uint)c*2) ^ (uint)((row&SWZ)<<4));
    *(uint4*)((char*)xs + byteoff) = make_uint4(pk[0],pk[1],pk[2],pk[3]);
  }
  __syncthreads();

  int lane = tid&63, wid = tid>>6;
  int l16 = lane&15, lhi = lane>>4;
  int colbase = (split*4 + wid) * (OUT/(4*NSPLIT));
  f32x4 acc[ROWT][WCOLT];
  #pragma unroll
  for(int m=0;m<ROWT;m++)
    #pragma unroll
    for(int n=0;n<WCOLT;n++) acc[m][n]=(f32x4){0,0,0,0};
  int rowc[ROWT];
  #pragma unroll
  for(int m=0;m<ROWT;m++){ int r=m*16+l16; rowc[m]=(r/20)*22 + (r%20); }
  const ushort* wptile[WCOLT];
  #pragma unroll
  for(int n=0;n<WCOLT;n++)
    wptile[n] = wt + ((size_t)(colbase/16 + n)*KSTEPS)*512 + (size_t)lane*8;

  short8 aF0[ROWT], bF0[WCOLT], aF1[ROWT], bF1[WCOLT];

#define LOADK(ksv, A, B) { \
    int t_=(ksv)/(CIN/32); int c0_=((ksv)%(CIN/32))*32 + lhi*8; \
    _Pragma("unroll") \
    for(int m=0;m<ROWT;m++){ \
      int row_=rowc[m]+t_; \
      uint off_=(uint)row_*RB + (((uint)c0_*2) ^ (uint)((row_&SWZ)<<4)); \
      A[m]=*(const short8*)((char*)xs+off_); } \
    _Pragma("unroll") \
    for(int n=0;n<WCOLT;n++) B[n]=*(const short8*)(wptile[n]+(ksv)*512); }

#define MFMAK(A, B) { \
    _Pragma("unroll") \
    for(int m=0;m<ROWT;m++) \
      _Pragma("unroll") \
      for(int n=0;n<WCOLT;n++) \
        acc[m][n]=__builtin_amdgcn_mfma_f32_16x16x32_bf16(A[m],B[n],acc[m][n],0,0,0); }

  LOADK(0, aF0, bF0);
  #pragma unroll
  for(int kp=0; kp<KSTEPS/2; kp++){
    int ks = kp*2;
    LOADK(ks+1, aF1, bF1);
    MFMAK(aF0, bF0);
    if(ks+2<KSTEPS) LOADK(ks+2, aF0, bF0);
    MFMAK(aF1, bF1);
  }
#undef LOADK
#undef MFMAK

  #pragma unroll
  for(int n=0;n<WCOLT;n++){
    float s=0,q=0;
    #pragma unroll
    for(int m=0;m<ROWT;m++)
      #pragma unroll
      for(int j=0;j<4;j++){ float a=acc[m][n][j]; s+=a; q+=a*a; }
    s += __shfl_xor(s,16); s += __shfl_xor(s,32);
    q += __shfl_xor(q,16); q += __shfl_xor(q,32);
    if(lhi==0){
      int o = colbase+n*16+l16;
      atomicAdd(&ws[soOut+o], s);
      atomicAdd(&ws[soOutQ+o], q);
    }
  }
  ushort* dst = yout + (size_t)eblk*M*OUT;
  #pragma unroll
  for(int m=0;m<ROWT;m++)
    #pragma unroll
    for(int j=0;j<4;j++){
      int R = m*16 + lhi*4 + j;
      #pragma unroll
      for(int n=0;n<WCOLT;n++)
        dst[(size_t)R*OUT + colbase + n*16 + l16] = f2bf(acc[m][n][j]);
    }
}

// -------- fused pool+fc --------
__global__ __launch_bounds__(256) void k_poolfc(const float* __restrict__ fcw, float* __restrict__ ws){
  __shared__ float ps[16][260];
  __shared__ float red[4][32];
  __shared__ float mo[256][2];
  int tid=threadIdx.x;
  {
    float m=ws[SO_C3+tid]*(1.0f/81920.0f);
    float v=ws[SO_C3Q+tid]*(1.0f/81920.0f)-m*m; if(v<0)v=0;
    mo[tid][0]=m; mo[tid][1]=rsqrtf(v+EPSB);
  }
  __syncthreads();
  int e0=blockIdx.x*16;
  const ushort* y3=(const ushort*)(ws+F_Y13);
  float m=mo[tid][0], inv=mo[tid][1];
  for(int el=0;el<16;el++){
    const ushort* row=y3+((size_t)(e0+el)*20)*256+tid;
    float s=0;
    #pragma unroll
    for(int l=0;l<20;l++){
      float x=(bf2f(row[(size_t)l*256])-m)*inv;
      s += x>=0.f? x : 0.01f*x;
    }
    ps[el][tid]=s*(1.0f/20.0f);
  }
  __syncthreads();
  int e=tid>>4, h=tid&15;
  const float* wr=fcw+(size_t)h*256;
  float z=0;
  for(int c=0;c<256;c++) z+=ps[e][c]*wr[c];
  ws[F_FCB+(size_t)(e0+e)*16+h]=z;
  float s=z, q=z*z;
  #pragma unroll
  for(int o=16;o<64;o<<=1){ s+=__shfl_down(s,o); q+=__shfl_down(q,o); }
  int lane=tid&63, wid=tid>>6;
  if(lane<16){ red[wid][lane]=s; red[wid][16+lane]=q; }
  __syncthreads();
  if(tid<32){
    float v=red[0][tid]+red[1][tid]+red[2][tid]+red[3][tid];
    atomicAdd(&ws[tid<16? SO_FC+tid : SO_FCQ+(tid-16)], v);
  }
}

// -------- fused ef + edgeconv layer1: ef inline -> agg -> z1ec + stats --------
__device__ __constant__ int EF_BASES[4][2] = {
  {SO_ET2,SO_ET2Q},{SO_EL2,SO_EL2Q},{SO_EV2,SO_EV2Q},{SO_FC,SO_FCQ}
};

__global__ __launch_bounds__(256) void k_aggef(const int* __restrict__ src, const int* __restrict__ dst,
    const float* __restrict__ ecW1, float* __restrict__ ws){
  __shared__ float w1s[1024];
  __shared__ float mi[4][16][2];
  int tid=threadIdx.x;
  for(int i=tid;i<1024;i+=256) w1s[i]=ecW1[i];
  if(tid<64){
    int g=tid>>4, h=tid&15;
    float m=ws[EF_BASES[g][0]+h]*(1.0f/4096.0f);
    float v=ws[EF_BASES[g][1]+h]*(1.0f/4096.0f)-m*m; if(v<0)v=0;
    mi[g][h][0]=m; mi[g][h][1]=rsqrtf(v+EPSB);
  }
  __syncthreads();
  int e=blockIdx.x*256+tid;
  float a[16];
  #pragma unroll
  for(int h=0;h<16;h++){
    float z=ws[F_FCB+(size_t)e*16+h];
    a[h]=(z-mi[3][h][0])*mi[3][h][1];     // fc: BN, no relu
  }
  #pragma unroll
  for(int g=0;g<3;g++){
    const float* z2=ws+F_Z2T+(size_t)g*65536;
    #pragma unroll
    for(int k=0;k<16;k++){
      float z=z2[(size_t)e*16+k];
      float r=(z-mi[g][k][0])*mi[g][k][1];
      a[k]+= r>0?r:0;
    }
  }
  int s=src[e], d=dst[e];
  #pragma unroll
  for(int h=0;h<16;h++)
    a[h]+=ws[F_PROJ+(size_t)s*16+h]+ws[F_PROJ+(size_t)d*16+h];
  int lane=tid&63;
  for(int o=0;o<64;o++){
    float z=0;
    #pragma unroll
    for(int h=0;h<16;h++) z+=w1s[o*16+h]*a[h];
    ws[F_Z1EC+(size_t)e*64+o]=z;
    float rs=waveSum(z), rq=waveSum(z*z);
    if(lane==0){ atomicAdd(&ws[SO_G1+o],rs); atomicAdd(&ws[SO_G1Q+o],rq); }
  }
}

// ---------------- edgeconv layer2 -> z2 [E,16] (in F_FCB) + stats ----------------
__global__ __launch_bounds__(256) void k_ec2(const float* __restrict__ ecW2, float* __restrict__ ws){
  __shared__ float w2s[1024];
  __shared__ float mi[64][2];
  __shared__ float red[4][32];
  int tid=threadIdx.x;
  for(int i=tid;i<1024;i+=256) w2s[i]=ecW2[i];
  if(tid<64){
    float m=ws[SO_G1+tid]*(1.0f/4096.0f);
    float v=ws[SO_G1Q+tid]*(1.0f/4096.0f)-m*m; if(v<0)v=0;
    mi[tid][0]=m; mi[tid][1]=rsqrtf(v+EPSB);
  }
  __syncthreads();
  int e=blockIdx.x*256+tid;
  float acc[16];
  #pragma unroll
  for(int k=0;k<16;k++) acc[k]=0;
  for(int o=0;o<64;o++){
    float z=ws[F_Z1EC+(size_t)e*64+o];
    float h=(z-mi[o][0])*mi[o][1];
    h=h>0?h:0;
    #pragma unroll
    for(int k=0;k<16;k++) acc[k]+=w2s[k*64+o]*h;
  }
  float s[16], q[16];
  #pragma unroll
  for(int k=0;k<16;k++){
    ws[F_FCB+(size_t)e*16+k]=acc[k];
    s[k]=acc[k]; q[k]=acc[k]*acc[k];
  }
  int lane=tid&63, wid=tid>>6;
  #pragma unroll
  for(int k=0;k<16;k++){
    float rs=waveSum(s[k]), rq=waveSum(q[k]);
    if(lane==0){ red[wid][k]=rs; red[wid][16+k]=rq; }
  }
  __syncthreads();
  if(tid<32){
    float t=red[0][tid]+red[1][tid]+red[2][tid]+red[3][tid];
    atomicAdd(&ws[tid<16 ? SO_G2+tid : SO_G2Q+(tid-16)], t);
  }
}

// -------- edge_feature + per-hop projection: G[b][pos][d][16] = Wd^T . edgef --------
__global__ __launch_bounds__(256) void k_ef2g(const float* __restrict__ edisw, float* __restrict__ ws){
  __shared__ float wd[1280];
  __shared__ float mi[16][2];
  int tid=threadIdx.x;
  for(int i=tid;i<1280;i+=256) wd[i]=edisw[i];
  if(tid<16){
    float m=ws[SO_G2+tid]*(1.0f/4096.0f);
    float va=ws[SO_G2Q+tid]*(1.0f/4096.0f)-m*m; if(va<0)va=0;
    mi[tid][0]=m; mi[tid][1]=rsqrtf(va+EPSB);
  }
  __syncthreads();
  int t=blockIdx.x*256+tid;
  if(t>=4*1025) return;
  int b=t/1025, pos=t%1025;
  float ef[16];
  if(pos<1024){
    int e=b*1024+pos;
    #pragma unroll
    for(int k=0;k<16;k++){
      float z=ws[F_FCB+(size_t)e*16+k];
      float v=(z-mi[k][0])*mi[k][1];
      ef[k]= v>0?v:0;
    }
  } else {
    #pragma unroll
    for(int k=0;k<16;k++) ef[k]=0;
  }
  float* g=ws+F_G+(size_t)t*80;
  #pragma unroll
  for(int d=0;d<5;d++){
    const float* wdd=wd+d*256;
    #pragma unroll
    for(int k=0;k<16;k++){
      float s=0;
      #pragma unroll
      for(int h=0;h<16;h++) s+=ef[h]*wdd[h*16+k];
      g[d*16+k]=s;
    }
  }
}

// ---------------- main per-pair kernel ----------------
__global__ __launch_bounds__(256) void k_pair(const float* __restrict__ ab,
    const int* __restrict__ sd, const float* __restrict__ ang, const float* __restrict__ cen,
    const int* __restrict__ ep, const float* __restrict__ sdemb,
    const float* __restrict__ angW1, const float* __restrict__ angW2,
    const float* __restrict__ cenW1, const float* __restrict__ cenW2,
    const float* __restrict__ ws, float* __restrict__ out){
  __shared__ float cpa[16],cma[16],m2a[16],i2a[16];
  __shared__ float cpc[16],cmc[16],m2c[16],i2c[16];
  __shared__ float mv[4];
  int tid=threadIdx.x;
  if(tid==0){
    float s=ws[SO_ANGX], q=ws[SO_ANGX+1];
    float mu=s*(1.0f/262144.0f);
    float v=q*(1.0f/262144.0f)-mu*mu; if(v<0)v=0;
    mv[0]=mu; mv[1]=v;
    s=ws[SO_CENX]; q=ws[SO_CENX+1];
    mu=s*(1.0f/262144.0f);
    v=q*(1.0f/262144.0f)-mu*mu; if(v<0)v=0;
    mv[2]=mu; mv[3]=v;
  }
  __syncthreads();
  if(tid<32){
    int k=tid&15; bool isC = tid>=16;
    const float* W1=isC?cenW1:angW1; const float* W2=isC?cenW2:angW2;
    float var=isC?mv[3]:mv[1];
    float cp=0, cm=0;
    for(int h=0;h<16;h++){
      float w=W1[h];
      float A=w*rsqrtf(var*w*w+EPSB);
      float wk=W2[k*16+h];
      if(A>0) cp+=wk*A; else cm+=wk*A;
    }
    int mo = isC? SO_MOMC : SO_MOMA;
    float P=ws[mo], N=ws[mo+1], Pq=ws[mo+2], Nq=ws[mo+3];
    float mean=(cp*P+cm*N)*(1.0f/262144.0f);
    float e2=(cp*cp*Pq+cm*cm*Nq)*(1.0f/262144.0f);
    float v2=e2-mean*mean; if(v2<0)v2=0;
    float iv=rsqrtf(v2+EPSB);
    if(!isC){ cpa[k]=cp; cma[k]=cm; m2a[k]=mean; i2a[k]=iv; }
    else    { cpc[k]=cp; cmc[k]=cm; m2c[k]=mean; i2c[k]=iv; }
  }
  __syncthreads();
  int t=blockIdx.x*256+tid;            // b,i,j
  int b=t>>16, rem=t&65535, i=rem>>8, j=rem&255;
  int sdv=sd[t];
  float xa=ang[t], xc0=cen[t];
  float acc[16];
  const float* se=sdemb+(size_t)sdv*16;
  #pragma unroll
  for(int k=0;k<16;k++) acc[k]=se[k];
  { // angle (closed form)
    float dx=xa-mv[0];
    bool pos=dx>0.f;
    #pragma unroll
    for(int k=0;k<16;k++){
      float z=dx*(pos?cpa[k]:cma[k]);
      float r=(z-m2a[k])*i2a[k];
      acc[k]+= r>0?r:0;
    }
  }
  { // centroid (closed form)
    float dx=xc0-mv[2];
    bool pos=dx>0.f;
    #pragma unroll
    for(int k=0;k<16;k++){
      float z=dx*(pos?cpc[k]:cmc[k]);
      float r=(z-m2c[k])*i2c[k];
      acc[k]+= r>0?r:0;
    }
  }
  { // multi-hop edge bias via precomputed G
    int sdm = sdv==0 ? 1 : sdv;
    if(sdm>1) sdm-=1;
    if(sdm>5) sdm=5;
    float inv=1.0f/((float)sdm+1e-6f);
    float eb[16];
    #pragma unroll
    for(int k=0;k<16;k++) eb[k]=0;
    const float* G=ws+F_G;
    #pragma unroll
    for(int d=0;d<5;d++){
      int idx=ep[(size_t)t*5+d];
      const float4* g=(const float4*)(G+((size_t)(b*1025+idx)*5+d)*16);
      float4 g0=g[0], g1=g[1], g2=g[2], g3=g[3];
      eb[0]+=g0.x; eb[1]+=g0.y; eb[2]+=g0.z; eb[3]+=g0.w;
      eb[4]+=g1.x; eb[5]+=g1.y; eb[6]+=g1.z; eb[7]+=g1.w;
      eb[8]+=g2.x; eb[9]+=g2.y; eb[10]+=g2.z; eb[11]+=g2.w;
      eb[12]+=g3.x; eb[13]+=g3.y; eb[14]+=g3.z; eb[15]+=g3.w;
    }
    #pragma unroll
    for(int k=0;k<16;k++) acc[k]+=eb[k]*inv;
  }
  float base2=2.0f*ab[(size_t)b*66049+(size_t)(i+1)*257+(j+1)];
  #pragma unroll
  for(int k=0;k<16;k++)
    out[(((size_t)b*16+k)*257+(i+1))*257+(j+1)]=acc[k]+base2;
}

// ---------------- borders ----------------
__global__ __launch_bounds__(256) void k_border(const float* __restrict__ ab,
    const float* __restrict__ virt, float* __restrict__ out){
  int t=blockIdx.x*256+threadIdx.x;
  if(t>=4*16*513) return;
  int idx=t%513, bh=t/513;
  int b=bh>>4, h=bh&15;
  float v=virt[h];
  if(idx<257){
    out[(((size_t)b*16+h)*257)*257+idx]=2.0f*ab[(size_t)b*66049+idx]+v;
  } else {
    int p=idx-256;
    out[(((size_t)b*16+h)*257+p)*257]=2.0f*ab[(size_t)b*66049+(size_t)p*257]+v;
  }
}

extern "C" void kernel_launch(void* const* d_in, const int* in_sizes, int n_in,
                              void* d_out, int out_size, void* d_ws, size_t ws_size,
                              hipStream_t stream) {
  const float* ab    =(const float*)d_in[0];
  const int*   sdist =(const int*)  d_in[1];
  const float* ang   =(const float*)d_in[2];
  const float* cen   =(const float*)d_in[3];
  const int*   ep    =(const int*)  d_in[4];
  const float* edata =(const float*)d_in[5];
  const float* etype =(const float*)d_in[6];
  const float* elen  =(const float*)d_in[7];
  const float* econv =(const float*)d_in[8];
  const int*   src   =(const int*)  d_in[10];
  const int*   dst   =(const int*)  d_in[11];
  const float* nf    =(const float*)d_in[12];
  const float* sdemb =(const float*)d_in[13];
  const float* virt  =(const float*)d_in[14];
  const float* angW1 =(const float*)d_in[15];
  const float* angW2 =(const float*)d_in[16];
  const float* cenW1 =(const float*)d_in[17];
  const float* cenW2 =(const float*)d_in[18];
  const float* etW1  =(const float*)d_in[19];
  const float* etW2  =(const float*)d_in[20];
  const float* elW1  =(const float*)d_in[21];
  const float* elW2  =(const float*)d_in[22];
  const float* evW1  =(const float*)d_in[23];
  const float* evW2  =(const float*)d_in[24];
  const float* c1w   =(const float*)d_in[25];
  const float* c2w   =(const float*)d_in[26];
  const float* c3w   =(const float*)d_in[27];
  const float* fcw   =(const float*)d_in[28];
  const float* edisw =(const float*)d_in[29];
  const float* ecWp  =(const float*)d_in[30];
  const float* ecW1  =(const float*)d_in[31];
  const float* ecW2  =(const float*)d_in[32];
  float* ws=(float*)d_ws;
  float* out=(float*)d_out;

  hipMemsetAsync(d_ws, 0, STATS_FLOATS*sizeof(float), stream);

  k_front<<<1104,256,0,stream>>>(edata,c1w,c2w,c3w,nf,ecWp,ang,cen,
                                 etype,elen,econv,etW1,elW1,evW1,ws);
  k_stats2<<<112,256,0,stream>>>(ang,cen,etype,elen,econv,
                                 etW1,etW2,elW1,elW2,evW1,evW2,ws);

  k_convmf<64,128,4,1><<<1024,256,0,stream>>>((const ushort*)(ws+F_Y13),(const ushort*)(ws+F_WT2),
                                              (ushort*)(ws+F_Y2),ws,SO_C1,SO_C1Q,SO_C2,SO_C2Q);
  k_convmf<128,256,4,2><<<2048,256,0,stream>>>((const ushort*)(ws+F_Y2),(const ushort*)(ws+F_WT3),
                                               (ushort*)(ws+F_Y13),ws,SO_C2,SO_C2Q,SO_C3,SO_C3Q);
  k_poolfc<<<256,256,0,stream>>>(fcw,ws);

  k_aggef<<<16,256,0,stream>>>(src,dst,ecW1,ws);
  k_ec2<<<16,256,0,stream>>>(ecW2,ws);
  k_ef2g<<<17,256,0,stream>>>(edisw,ws);

  k_pair<<<1024,256,0,stream>>>(ab,sdist,ang,cen,ep,sdemb,angW1,angW2,cenW1,cenW2,ws,out);
  k_border<<<129,256,0,stream>>>(ab,virt,out);
}